// Round 12
// baseline (108.483 us; speedup 1.0000x reference)
//
#include <hip/hip_runtime.h>

typedef short short8 __attribute__((ext_vector_type(8)));
typedef short short4v __attribute__((ext_vector_type(4)));
typedef float f32x4 __attribute__((ext_vector_type(4)));
typedef float f32x16 __attribute__((ext_vector_type(16)));
typedef unsigned int uint4v __attribute__((ext_vector_type(4)));
typedef unsigned int uint2v __attribute__((ext_vector_type(2)));

#define NB 4
#define CD 256
#define ID 128
#define NP 4096

static __device__ __forceinline__ short f2bf(float f){
  unsigned u = __float_as_uint(f);
  u += 0x7FFF + ((u >> 16) & 1);
  return (short)(u >> 16);
}
static __device__ __forceinline__ float bf2f(short s){
  unsigned u = ((unsigned)(unsigned short)s) << 16;
  return __uint_as_float(u);
}
static __device__ __forceinline__ unsigned cvtpk(float lo, float hi){
  unsigned r;
  asm("v_cvt_pk_bf16_f32 %0, %1, %2" : "=v"(r) : "v"(lo), "v"(hi));
  return r;
}
static __device__ __forceinline__ float fexp2(float x){
  float r;
  asm("v_exp_f32 %0, %1" : "=v"(r) : "v"(x));
  return r;
}
static __device__ __forceinline__ unsigned pack4_fp8(float a, float b, float c, float d){
  unsigned lo, hi;
  asm("v_cvt_pk_fp8_f32 %0, %1, %2" : "=v"(lo) : "v"(a), "v"(b));
  asm("v_cvt_pk_fp8_f32 %0, %1, %2" : "=v"(hi) : "v"(c), "v"(d));
  return (lo & 0xffffu) | (hi << 16);
}
static __device__ __forceinline__ unsigned char f2fp8(float v){
  unsigned u;
  asm("v_cvt_pk_fp8_f32 %0, %1, %1" : "=v"(u) : "v"(v));
  return (unsigned char)u;
}

static __device__ __forceinline__ void gload16(const void* g, void* l){
  __builtin_amdgcn_global_load_lds(
      (const __attribute__((address_space(1))) unsigned int*)g,
      (__attribute__((address_space(3))) unsigned int*)l, 16, 0, 0);
}

// ---------------- weights fp32 -> bf16 (g, theta, phi, out concatenated) ----
__global__ __launch_bounds__(256) void k_cvtw(const float* __restrict__ g_w,
    const float* __restrict__ th_w, const float* __restrict__ ph_w,
    const float* __restrict__ out_w, short* __restrict__ wb){
  int idx = (blockIdx.x * 256 + threadIdx.x) * 4;
  const float* s;
  int sel = idx >> 15;
  if(sel == 0) s = g_w; else if(sel == 1) s = th_w; else if(sel == 2) s = ph_w; else s = out_w;
  int off = idx & 32767;
  float4 v = *reinterpret_cast<const float4*>(s + off);
  short4v o = { f2bf(v.x), f2bf(v.y), f2bf(v.z), f2bf(v.w) };
  *reinterpret_cast<short4v*>(wb + idx) = o;
}

// ---------------- x (n,C,N) fp32 -> xt (n,N,C) bf16 -------------------------
__global__ __launch_bounds__(256) void k_transpose(const float* __restrict__ x,
                                                   short* __restrict__ xt){
  __shared__ float T[64][68];
  int n = blockIdx.z, c0 = blockIdx.y * 64, p0 = blockIdx.x * 64;
  int t = threadIdx.x;
  const float* xp = x + ((size_t)(n * CD + c0)) * NP + p0;
#pragma unroll
  for(int it = 0; it < 4; ++it){
    int c = (t >> 4) + it * 16;
    int p = (t & 15) * 4;
    float4 v = *reinterpret_cast<const float4*>(xp + (size_t)c * NP + p);
    T[c][p+0] = v.x; T[c][p+1] = v.y; T[c][p+2] = v.z; T[c][p+3] = v.w;
  }
  __syncthreads();
  short* op = xt + ((size_t)(n * NP + p0)) * CD + c0;
  int p = t >> 2, cc = (t & 3) * 16;
  short8 a, b;
#pragma unroll
  for(int j = 0; j < 8; ++j){ a[j] = f2bf(T[cc + j][p]); b[j] = f2bf(T[cc + 8 + j][p]); }
  *reinterpret_cast<short8*>(op + (size_t)p * CD + cc) = a;
  *reinterpret_cast<short8*>(op + (size_t)p * CD + cc + 8) = b;
}

// ---------------- fused projections (LDS-staged, weight-stationary) ---------
__global__ __launch_bounds__(512) void k_proj(const short* __restrict__ xt,
    const short* __restrict__ wb, const float* __restrict__ g_b,
    const float* __restrict__ th_b, const float* __restrict__ ph_b,
    unsigned char* __restrict__ q8, unsigned char* __restrict__ k8,
    unsigned char* __restrict__ v8){
  __shared__ __align__(16) char XT[32768];
  int b = blockIdx.x;
  int n = b >> 6, pt = b & 63;
  int pb0 = pt * 64;
  int t = threadIdx.x, w = t >> 6, l = t & 63;
  int lr = l & 15, lg = l >> 4;
  int i0 = w * 16;

  const char* xg = (const char*)(xt + ((size_t)(n * NP + pb0)) * CD);
#pragma unroll
  for(int i_ = 0; i_ < 4; ++i_){
    int dd = t * 16 + i_ * 8192;
    int row = dd >> 9;
    int sz = (dd & ~511) | ((dd & 511) ^ ((row & 15) << 4));
    gload16(xg + sz, XT + dd);
  }

  const short* gww = wb;
  const short* thw = wb + 32768;
  const short* phw = wb + 65536;
  short8 Wt[8], Wp[8], Wg[8];
#pragma unroll
  for(int kk = 0; kk < 8; ++kk){
    size_t wo = (size_t)(i0 + lr) * CD + kk * 32 + lg * 8;
    Wt[kk] = *reinterpret_cast<const short8*>(thw + wo);
    Wp[kk] = *reinterpret_cast<const short8*>(phw + wo);
    Wg[kk] = *reinterpret_cast<const short8*>(gww + wo);
  }
  float bt = th_b[i0 + lr];
  float bp = ph_b[i0 + lr];
  float gb[4];
#pragma unroll
  for(int r = 0; r < 4; ++r) gb[r] = g_b[i0 + lg * 4 + r];

  __syncthreads();

  size_t pan = ((size_t)n * 64 + pt) * 64;
#pragma unroll
  for(int psub = 0; psub < 4; ++psub){
    int prow = psub * 16 + lr;
    short8 X[8];
#pragma unroll
    for(int kk = 0; kk < 8; ++kk)
      X[kk] = *reinterpret_cast<const short8*>(
          XT + prow * 512 + ((kk * 64 + lg * 16) ^ ((prow & 15) << 4)));
    f32x4 aT = {0.f,0.f,0.f,0.f}, aP = {0.f,0.f,0.f,0.f}, aG = {0.f,0.f,0.f,0.f};
#pragma unroll
    for(int kk = 0; kk < 8; ++kk){
      aT = __builtin_amdgcn_mfma_f32_16x16x32_bf16(X[kk], Wt[kk], aT, 0, 0, 0);
      aP = __builtin_amdgcn_mfma_f32_16x16x32_bf16(X[kk], Wp[kk], aP, 0, 0, 0);
      aG = __builtin_amdgcn_mfma_f32_16x16x32_bf16(Wg[kk], X[kk], aG, 0, 0, 0);
    }
#pragma unroll
    for(int r = 0; r < 4; ++r){
      size_t o = ((size_t)(n * NP + pb0 + psub * 16 + lg * 4 + r)) * ID + i0 + lr;
      q8[o] = f2fp8((aT[r] + bt) * 1.44269504f);   // log2(e) folded for exp2
      k8[o] = f2fp8(aP[r] + bp);
    }
#pragma unroll
    for(int r = 0; r < 4; ++r){
      int ii = i0 + lg * 4 + r;
      v8[(pan + (ii >> 1)) * 128 + (ii & 1) * 64 + psub * 16 + lr] = f2fp8(aG[r] + gb[r]);
    }
  }
}

// ---------------- flash attention, fp8, swapped-QK 32x32, q=64/wave ---------
// 128-thr blocks (2 waves x 64 q), grid 512 = n(4) x kq(4) x qtl(32);
// 4 blocks/CU = 8 waves/CU (2/SIMD). Each Kf/Vf LDS read feeds 2 MFMAs
// (q-sets) -> LDS bytes per MFMA halved vs 32q. K [64k][128c] fp8 + V paired
// [64r][128] fp8 LDS dbuf via swizzled-source global_load_lds. P in regs
// (v_cvt_pk_fp8_f32 + permlane32_swap). exp2 with fixed -4 shift.
__global__ __launch_bounds__(128, 2) void k_attn(const unsigned char* __restrict__ q8,
    const unsigned char* __restrict__ k8, const unsigned char* __restrict__ v8,
    short* __restrict__ po, float* __restrict__ psums){
  __shared__ __align__(16) char smem[32768];   // loop: K dbuf 16K | V dbuf 16K; epi: 2x16K ow
  int b = blockIdx.x;
  int xcd = b & 7;
  int n = xcd >> 1;                            // batch pinned to 2 XCDs
  int kq = ((xcd & 1) << 1) | ((b >> 3) & 1);
  int qtl = b >> 4;                            // 0..31
  int t = threadIdx.x, w = t >> 6, l = t & 63;
  int q31 = l & 31, hi = l >> 5;
  int pbase = qtl * 128 + w * 64;

  const char* kpanel = (const char*)k8 + ((size_t)(n * NP + kq * 1024)) * ID;
  const char* vpanel = (const char*)v8 + ((size_t)n * 64 + kq * 16) * 8192;
  const char* qbase  = (const char*)q8 + ((size_t)(n * NP + pbase)) * ID;

  // Q B-frags: two q-sets of 32 rows
  uint2v Qf[2][8];
#pragma unroll
  for(int qs = 0; qs < 2; ++qs)
#pragma unroll
    for(int cst = 0; cst < 8; ++cst)
      Qf[qs][cst] = *reinterpret_cast<const uint2v*>(
          qbase + (qs * 32 + q31) * 128 + cst * 16 + hi * 8);

  f32x16 Of[2][4];
#pragma unroll
  for(int qs = 0; qs < 2; ++qs)
#pragma unroll
    for(int db = 0; db < 4; ++db)
#pragma unroll
      for(int r = 0; r < 16; ++r) Of[qs][db][r] = 0.f;
  float ps[2] = {0.f, 0.f};

#define STAGE(cb, kt_) do { \
    const char* kg_ = kpanel + (size_t)(kt_) * 8192; \
    const char* vg_ = vpanel + (size_t)(kt_) * 8192; \
    char* kld_ = smem + (cb) * 8192; \
    char* vld_ = smem + 16384 + (cb) * 8192; \
    _Pragma("unroll") \
    for(int i_ = 0; i_ < 4; ++i_){ \
      int dd = t * 16 + i_ * 2048; \
      int sz = (dd & ~127) | ((dd & 127) ^ (((dd >> 7) & 7) << 4)); \
      gload16(kg_ + sz, kld_ + dd); \
      gload16(vg_ + sz, vld_ + dd); \
    } \
  } while(0)

  STAGE(0, 0);
  __syncthreads();

#pragma unroll 2
  for(int kt = 0; kt < 16; ++kt){
    const int pb = kt & 1;
    if(kt + 1 < 16) STAGE(pb ^ 1, kt + 1);
    const char* Kc = smem + pb * 8192;
    const char* Vc = smem + 16384 + pb * 8192;
#pragma unroll
    for(int kb = 0; kb < 2; ++kb){
      // ---- S^T = mfma(K, Q); one Kf read feeds both q-sets ----
      f32x16 S0, S1;
#pragma unroll
      for(int r = 0; r < 16; ++r){ S0[r] = 0.f; S1[r] = 0.f; }
      int krow = kb * 32 + q31;
      __builtin_amdgcn_s_setprio(1);
#pragma unroll
      for(int cst = 0; cst < 8; ++cst){
        uint2v Kf = *reinterpret_cast<const uint2v*>(
            Kc + krow * 128 + ((cst * 16) ^ ((krow & 7) << 4)) + hi * 8);
        long Kl = __builtin_bit_cast(long, Kf);
        S0 = __builtin_amdgcn_mfma_f32_32x32x16_fp8_fp8(
            Kl, __builtin_bit_cast(long, Qf[0][cst]), S0, 0, 0, 0);
        S1 = __builtin_amdgcn_mfma_f32_32x32x16_fp8_fp8(
            Kl, __builtin_bit_cast(long, Qf[1][cst]), S1, 0, 0, 0);
      }
      __builtin_amdgcn_s_setprio(0);
      // ---- exp2 (-4 shift, cancels in norm), per-lane sums, pack fp8 ----
      uint2v Pf[2][2];
#pragma unroll
      for(int qs = 0; qs < 2; ++qs){
        float e[16];
#pragma unroll
        for(int r = 0; r < 16; ++r) e[r] = fexp2((qs ? S1[r] : S0[r]) - 4.0f);
#pragma unroll
        for(int r = 0; r < 16; ++r) ps[qs] += e[r];
        unsigned u0 = pack4_fp8(e[0],  e[1],  e[2],  e[3]);
        unsigned u1 = pack4_fp8(e[4],  e[5],  e[6],  e[7]);
        unsigned u2 = pack4_fp8(e[8],  e[9],  e[10], e[11]);
        unsigned u3 = pack4_fp8(e[12], e[13], e[14], e[15]);
        asm("v_permlane32_swap_b32 %0, %1" : "+v"(u0), "+v"(u1));
        asm("v_permlane32_swap_b32 %0, %1" : "+v"(u2), "+v"(u3));
        Pf[qs][0] = uint2v{u0, u1};
        Pf[qs][1] = uint2v{u2, u3};
      }
      // ---- PV: one Vf read feeds both q-sets ----
      __builtin_amdgcn_s_setprio(1);
#pragma unroll
      for(int cc = 0; cc < 2; ++cc){
        long P0 = __builtin_bit_cast(long, Pf[0][cc]);
        long P1 = __builtin_bit_cast(long, Pf[1][cc]);
#pragma unroll
        for(int db = 0; db < 4; ++db){
          int d = db * 32 + q31;
          int row = d >> 1;
          int off = (d & 1) * 64 + kb * 32 + cc * 16;
          uint2v Vf = *reinterpret_cast<const uint2v*>(
              Vc + row * 128 + ((off ^ ((row & 7) << 4))) + hi * 8);
          long Vl = __builtin_bit_cast(long, Vf);
          Of[0][db] = __builtin_amdgcn_mfma_f32_32x32x16_fp8_fp8(P0, Vl, Of[0][db], 0, 0, 0);
          Of[1][db] = __builtin_amdgcn_mfma_f32_32x32x16_fp8_fp8(P1, Vl, Of[1][db], 0, 0, 0);
        }
      }
      __builtin_amdgcn_s_setprio(0);
    }
    __syncthreads();
  }
#undef STAGE

  // ---- epilogue: row sums; O via per-wave LDS transpose bounce ----
#pragma unroll
  for(int qs = 0; qs < 2; ++qs){
    float pst = ps[qs] + __shfl_xor(ps[qs], 32);
    if(hi == 0)
      psums[(size_t)kq * 16384 + n * NP + pbase + qs * 32 + q31] = pst;
  }
  float* ow = (float*)(smem + w * 16384);    // [32 q][128 d] f32 per wave
  short* prb = po + ((size_t)kq * 16384 + n * NP + pbase) * ID;
#pragma unroll
  for(int qs = 0; qs < 2; ++qs){
#pragma unroll
    for(int reg = 0; reg < 16; ++reg){
      int q = (reg & 3) + 8 * (reg >> 2) + 4 * hi;
#pragma unroll
      for(int db = 0; db < 4; ++db)
        ow[q * 128 + db * 32 + q31] = Of[qs][db][reg];
    }
    asm volatile("s_waitcnt lgkmcnt(0)" ::: "memory");
    __builtin_amdgcn_sched_barrier(0);
    short* pr = prb + (size_t)(qs * 32) * ID;
#pragma unroll
    for(int it = 0; it < 8; ++it){
      int o = it * 1024 + l * 16;
      int q = o >> 8, d0 = (o & 255) >> 1;
      f32x4 va = *reinterpret_cast<const f32x4*>(ow + q * 128 + d0);
      f32x4 vb = *reinterpret_cast<const f32x4*>(ow + q * 128 + d0 + 4);
      uint4v pk4 = { cvtpk(va[0], va[1]), cvtpk(va[2], va[3]),
                     cvtpk(vb[0], vb[1]), cvtpk(vb[2], vb[3]) };
      *reinterpret_cast<short8*>(pr + (size_t)q * ID + d0) = __builtin_bit_cast(short8, pk4);
    }
    asm volatile("s_waitcnt lgkmcnt(0)" ::: "memory");   // drain before next qs overwrites
  }
}

// ---------------- fused: merge 4 k-partials + 1x1 conv + BN + residual ------
__global__ __launch_bounds__(512) void k_outproj(const short* __restrict__ po,
    const float* __restrict__ psums, const short* __restrict__ ow_b,
    const float* __restrict__ bng, const float* __restrict__ bnb,
    const float* __restrict__ bnm, const float* __restrict__ bnv,
    const float* __restrict__ x, float* __restrict__ out){
  __shared__ __align__(16) short XW[64 * 128];
  int b = blockIdx.x;
  int n = b >> 6, pt = b & 63;
  int pg0 = pt * 64;
  int t = threadIdx.x, w = t >> 6, l = t & 63;
  int lr = l & 15, lg = l >> 4;

  {
    int p = t >> 3, i0 = (t & 7) * 16;
    size_t qg = (size_t)n * NP + pg0 + p;
    float den = psums[qg] + psums[16384 + qg] + psums[32768 + qg] + psums[49152 + qg];
    float inv = 1.f / (16.f * den);
    const short* pp = po + qg * ID + i0;
    int key = (p & 15) << 4;
#pragma unroll
    for(int h = 0; h < 2; ++h){
      short8 b0 = *reinterpret_cast<const short8*>(pp + h * 8);
      short8 b1 = *reinterpret_cast<const short8*>(pp + (size_t)16384 * ID + h * 8);
      short8 b2 = *reinterpret_cast<const short8*>(pp + (size_t)32768 * ID + h * 8);
      short8 b3 = *reinterpret_cast<const short8*>(pp + (size_t)49152 * ID + h * 8);
      float f[8];
#pragma unroll
      for(int j = 0; j < 8; ++j)
        f[j] = (bf2f(b0[j]) + bf2f(b1[j]) + bf2f(b2[j]) + bf2f(b3[j])) * inv;
      uint4v pkv = { cvtpk(f[0], f[1]), cvtpk(f[2], f[3]),
                     cvtpk(f[4], f[5]), cvtpk(f[6], f[7]) };
      *reinterpret_cast<short8*>((char*)XW + p * 256 + ((i0 * 2 + h * 16) ^ key)) =
          __builtin_bit_cast(short8, pkv);
    }
  }
  __syncthreads();

  int c0 = w * 32;
  f32x4 acc[2][4];
#pragma unroll
  for(int mf = 0; mf < 2; ++mf)
#pragma unroll
    for(int nf = 0; nf < 4; ++nf) acc[mf][nf] = {0.f,0.f,0.f,0.f};
#pragma unroll
  for(int kk = 0; kk < 4; ++kk){
    short8 Af[2];
#pragma unroll
    for(int mf = 0; mf < 2; ++mf)
      Af[mf] = *reinterpret_cast<const short8*>(ow_b + (size_t)(c0 + mf * 16 + lr) * ID + kk * 32 + lg * 8);
#pragma unroll
    for(int nf = 0; nf < 4; ++nf){
      int prow = nf * 16 + lr;
      short8 Bf = *reinterpret_cast<const short8*>(
          (char*)XW + prow * 256 + ((kk * 64 + lg * 16) ^ ((prow & 15) << 4)));
#pragma unroll
      for(int mf = 0; mf < 2; ++mf)
        acc[mf][nf] = __builtin_amdgcn_mfma_f32_16x16x32_bf16(Af[mf], Bf, acc[mf][nf], 0, 0, 0);
    }
  }

#pragma unroll
  for(int mf = 0; mf < 2; ++mf){
    int cb = c0 + mf * 16 + lg * 4;
    float inv[4], sh[4];
#pragma unroll
    for(int r = 0; r < 4; ++r){
      float iv = bng[cb + r] * rsqrtf(bnv[cb + r] + 1e-5f);
      inv[r] = iv;
      sh[r] = bnb[cb + r] - bnm[cb + r] * iv;
    }
#pragma unroll
    for(int nf = 0; nf < 4; ++nf){
      int p = pg0 + nf * 16 + lr;
#pragma unroll
      for(int r = 0; r < 4; ++r){
        size_t idx = ((size_t)(n * CD + cb + r)) * NP + p;
        out[idx] = acc[mf][nf][r] * inv[r] + sh[r] + x[idx];
      }
    }
  }
}

extern "C" void kernel_launch(void* const* d_in, const int* in_sizes, int n_in,
                              void* d_out, int out_size, void* d_ws, size_t ws_size,
                              hipStream_t stream){
  const float* x    = (const float*)d_in[0];
  const float* g_w  = (const float*)d_in[1];
  const float* g_b  = (const float*)d_in[2];
  const float* th_w = (const float*)d_in[3];
  const float* th_b = (const float*)d_in[4];
  const float* ph_w = (const float*)d_in[5];
  const float* ph_b = (const float*)d_in[6];
  const float* out_w= (const float*)d_in[7];
  const float* bng  = (const float*)d_in[8];
  const float* bnb  = (const float*)d_in[9];
  const float* bnm  = (const float*)d_in[10];
  const float* bnv  = (const float*)d_in[11];
  float* out = (float*)d_out;
  char* ws = (char*)d_ws;

  short* xt          = (short*)(ws);                        // 8 MB  (n,N,C) bf16
  unsigned char* q8  = (unsigned char*)(ws + (size_t)(8u  << 20)); // 2 MB fp8
  unsigned char* k8  = (unsigned char*)(ws + (size_t)(12u << 20)); // 2 MB fp8
  unsigned char* v8  = (unsigned char*)(ws + (size_t)(16u << 20)); // 2 MB fp8 VL
  short* wb          = (short*)(ws + (size_t)(24u << 20));  // 256 KB bf16 weights
  short* po          = (short*)(ws + (size_t)(25u << 20));  // 16 MB partial O bf16
  float* psum        = (float*)(ws + (size_t)(41u << 20));  // 256 KB partial sums

  k_cvtw<<<128, 256, 0, stream>>>(g_w, th_w, ph_w, out_w, wb);
  k_transpose<<<dim3(64, 4, 4), 256, 0, stream>>>(x, xt);
  k_proj<<<256, 512, 0, stream>>>(xt, wb, g_b, th_b, ph_b, q8, k8, v8);
  k_attn<<<512, 128, 0, stream>>>(q8, k8, v8, po, psum);
  k_outproj<<<256, 512, 0, stream>>>(po, psum, wb + 98304, bng, bnb, bnm, bnv, x, out);
}

// Round 13
// 67.954 us; speedup vs baseline: 1.5964x; 1.5964x over previous
//
#include <hip/hip_runtime.h>

typedef short short8 __attribute__((ext_vector_type(8)));
typedef short short4v __attribute__((ext_vector_type(4)));
typedef float f32x4 __attribute__((ext_vector_type(4)));
typedef float f32x16 __attribute__((ext_vector_type(16)));
typedef unsigned int uint4v __attribute__((ext_vector_type(4)));
typedef unsigned int uint2v __attribute__((ext_vector_type(2)));

#define NB 4
#define CD 256
#define ID 128
#define NP 4096

static __device__ __forceinline__ short f2bf(float f){
  unsigned u = __float_as_uint(f);
  u += 0x7FFF + ((u >> 16) & 1);
  return (short)(u >> 16);
}
static __device__ __forceinline__ float bf2f(short s){
  unsigned u = ((unsigned)(unsigned short)s) << 16;
  return __uint_as_float(u);
}
static __device__ __forceinline__ unsigned cvtpk(float lo, float hi){
  unsigned r;
  asm("v_cvt_pk_bf16_f32 %0, %1, %2" : "=v"(r) : "v"(lo), "v"(hi));
  return r;
}
static __device__ __forceinline__ float fexp2(float x){
  float r;
  asm("v_exp_f32 %0, %1" : "=v"(r) : "v"(x));
  return r;
}
static __device__ __forceinline__ unsigned pack4_fp8(float a, float b, float c, float d){
  unsigned lo, hi;
  asm("v_cvt_pk_fp8_f32 %0, %1, %2" : "=v"(lo) : "v"(a), "v"(b));
  asm("v_cvt_pk_fp8_f32 %0, %1, %2" : "=v"(hi) : "v"(c), "v"(d));
  return (lo & 0xffffu) | (hi << 16);
}
static __device__ __forceinline__ unsigned char f2fp8(float v){
  unsigned u;
  asm("v_cvt_pk_fp8_f32 %0, %1, %1" : "=v"(u) : "v"(v));
  return (unsigned char)u;
}

static __device__ __forceinline__ void gload16(const void* g, void* l){
  __builtin_amdgcn_global_load_lds(
      (const __attribute__((address_space(1))) unsigned int*)g,
      (__attribute__((address_space(3))) unsigned int*)l, 16, 0, 0);
}

// ---------------- weights fp32 -> bf16 (g, theta, phi, out concatenated) ----
__global__ __launch_bounds__(256) void k_cvtw(const float* __restrict__ g_w,
    const float* __restrict__ th_w, const float* __restrict__ ph_w,
    const float* __restrict__ out_w, short* __restrict__ wb){
  int idx = (blockIdx.x * 256 + threadIdx.x) * 4;
  const float* s;
  int sel = idx >> 15;
  if(sel == 0) s = g_w; else if(sel == 1) s = th_w; else if(sel == 2) s = ph_w; else s = out_w;
  int off = idx & 32767;
  float4 v = *reinterpret_cast<const float4*>(s + off);
  short4v o = { f2bf(v.x), f2bf(v.y), f2bf(v.z), f2bf(v.w) };
  *reinterpret_cast<short4v*>(wb + idx) = o;
}

// ---------------- x (n,C,N) fp32 -> xt (n,N,C) bf16 -------------------------
__global__ __launch_bounds__(256) void k_transpose(const float* __restrict__ x,
                                                   short* __restrict__ xt){
  __shared__ float T[64][68];
  int n = blockIdx.z, c0 = blockIdx.y * 64, p0 = blockIdx.x * 64;
  int t = threadIdx.x;
  const float* xp = x + ((size_t)(n * CD + c0)) * NP + p0;
#pragma unroll
  for(int it = 0; it < 4; ++it){
    int c = (t >> 4) + it * 16;
    int p = (t & 15) * 4;
    float4 v = *reinterpret_cast<const float4*>(xp + (size_t)c * NP + p);
    T[c][p+0] = v.x; T[c][p+1] = v.y; T[c][p+2] = v.z; T[c][p+3] = v.w;
  }
  __syncthreads();
  short* op = xt + ((size_t)(n * NP + p0)) * CD + c0;
  int p = t >> 2, cc = (t & 3) * 16;
  short8 a, b;
#pragma unroll
  for(int j = 0; j < 8; ++j){ a[j] = f2bf(T[cc + j][p]); b[j] = f2bf(T[cc + 8 + j][p]); }
  *reinterpret_cast<short8*>(op + (size_t)p * CD + cc) = a;
  *reinterpret_cast<short8*>(op + (size_t)p * CD + cc + 8) = b;
}

// ---------------- fused projections (LDS-staged, weight-stationary) ---------
__global__ __launch_bounds__(512) void k_proj(const short* __restrict__ xt,
    const short* __restrict__ wb, const float* __restrict__ g_b,
    const float* __restrict__ th_b, const float* __restrict__ ph_b,
    unsigned char* __restrict__ q8, unsigned char* __restrict__ k8,
    unsigned char* __restrict__ v8){
  __shared__ __align__(16) char XT[32768];
  int b = blockIdx.x;
  int n = b >> 6, pt = b & 63;
  int pb0 = pt * 64;
  int t = threadIdx.x, w = t >> 6, l = t & 63;
  int lr = l & 15, lg = l >> 4;
  int i0 = w * 16;

  const char* xg = (const char*)(xt + ((size_t)(n * NP + pb0)) * CD);
#pragma unroll
  for(int i_ = 0; i_ < 4; ++i_){
    int dd = t * 16 + i_ * 8192;
    int row = dd >> 9;
    int sz = (dd & ~511) | ((dd & 511) ^ ((row & 15) << 4));
    gload16(xg + sz, XT + dd);
  }

  const short* gww = wb;
  const short* thw = wb + 32768;
  const short* phw = wb + 65536;
  short8 Wt[8], Wp[8], Wg[8];
#pragma unroll
  for(int kk = 0; kk < 8; ++kk){
    size_t wo = (size_t)(i0 + lr) * CD + kk * 32 + lg * 8;
    Wt[kk] = *reinterpret_cast<const short8*>(thw + wo);
    Wp[kk] = *reinterpret_cast<const short8*>(phw + wo);
    Wg[kk] = *reinterpret_cast<const short8*>(gww + wo);
  }
  float bt = th_b[i0 + lr];
  float bp = ph_b[i0 + lr];
  float gb[4];
#pragma unroll
  for(int r = 0; r < 4; ++r) gb[r] = g_b[i0 + lg * 4 + r];

  __syncthreads();

  size_t pan = ((size_t)n * 64 + pt) * 64;
#pragma unroll
  for(int psub = 0; psub < 4; ++psub){
    int prow = psub * 16 + lr;
    short8 X[8];
#pragma unroll
    for(int kk = 0; kk < 8; ++kk)
      X[kk] = *reinterpret_cast<const short8*>(
          XT + prow * 512 + ((kk * 64 + lg * 16) ^ ((prow & 15) << 4)));
    f32x4 aT = {0.f,0.f,0.f,0.f}, aP = {0.f,0.f,0.f,0.f}, aG = {0.f,0.f,0.f,0.f};
#pragma unroll
    for(int kk = 0; kk < 8; ++kk){
      aT = __builtin_amdgcn_mfma_f32_16x16x32_bf16(X[kk], Wt[kk], aT, 0, 0, 0);
      aP = __builtin_amdgcn_mfma_f32_16x16x32_bf16(X[kk], Wp[kk], aP, 0, 0, 0);
      aG = __builtin_amdgcn_mfma_f32_16x16x32_bf16(Wg[kk], X[kk], aG, 0, 0, 0);
    }
#pragma unroll
    for(int r = 0; r < 4; ++r){
      size_t o = ((size_t)(n * NP + pb0 + psub * 16 + lg * 4 + r)) * ID + i0 + lr;
      q8[o] = f2fp8((aT[r] + bt) * 1.44269504f);   // log2(e) folded for exp2
      k8[o] = f2fp8(aP[r] + bp);
    }
#pragma unroll
    for(int r = 0; r < 4; ++r){
      int ii = i0 + lg * 4 + r;
      v8[(pan + (ii >> 1)) * 128 + (ii & 1) * 64 + psub * 16 + lr] = f2fp8(aG[r] + gb[r]);
    }
  }
}

// ---------------- flash attention, fp8, swapped-QK 32x32, in-reg P ----------
// R10 measured-best: 4 waves x 32 q-rows, grid 512 (2 blocks/CU = 8 waves/CU),
// k-quarter (1024) in 16 steps of 64 k. K [64k][128c] fp8 + V paired
// [64r][128] fp8 LDS dbuf via swizzled-source global_load_lds.
// P in regs (v_cvt_pk_fp8_f32 + permlane32_swap). exp2 with fixed -4 shift.
__global__ __launch_bounds__(256, 2) void k_attn(const unsigned char* __restrict__ q8,
    const unsigned char* __restrict__ k8, const unsigned char* __restrict__ v8,
    short* __restrict__ po, float* __restrict__ psums){
  __shared__ __align__(16) char smem[65536];
  int b = blockIdx.x;
  int xcd = b & 7;
  int n = xcd >> 1;
  int kq = ((xcd & 1) << 1) | ((b >> 3) & 1);
  int qtl = b >> 4;
  int t = threadIdx.x, w = t >> 6, l = t & 63;
  int q31 = l & 31, hi = l >> 5;
  int pbase = qtl * 128 + w * 32;

  const char* kpanel = (const char*)k8 + ((size_t)(n * NP + kq * 1024)) * ID;
  const char* vpanel = (const char*)v8 + ((size_t)n * 64 + kq * 16) * 8192;
  const char* qbase  = (const char*)q8 + ((size_t)(n * NP + pbase)) * ID;

  uint2v Qf[8];
#pragma unroll
  for(int cst = 0; cst < 8; ++cst)
    Qf[cst] = *reinterpret_cast<const uint2v*>(qbase + q31 * 128 + cst * 16 + hi * 8);

  f32x16 Of[4];
#pragma unroll
  for(int db = 0; db < 4; ++db)
#pragma unroll
    for(int r = 0; r < 16; ++r) Of[db][r] = 0.f;
  float ps = 0.f;

#define STAGE(cb, kt_) do { \
    const char* kg_ = kpanel + (size_t)(kt_) * 8192; \
    const char* vg_ = vpanel + (size_t)(kt_) * 8192; \
    char* kld_ = smem + (cb) * 8192; \
    char* vld_ = smem + 16384 + (cb) * 8192; \
    _Pragma("unroll") \
    for(int i_ = 0; i_ < 2; ++i_){ \
      int dd = t * 16 + i_ * 4096; \
      int sz = (dd & ~127) | ((dd & 127) ^ (((dd >> 7) & 7) << 4)); \
      gload16(kg_ + sz, kld_ + dd); \
      gload16(vg_ + sz, vld_ + dd); \
    } \
  } while(0)

  STAGE(0, 0);
  __syncthreads();

#pragma unroll 2
  for(int kt = 0; kt < 16; ++kt){
    const int pb = kt & 1;
    if(kt + 1 < 16) STAGE(pb ^ 1, kt + 1);
    const char* Kc = smem + pb * 8192;
    const char* Vc = smem + 16384 + pb * 8192;
#pragma unroll
    for(int kb = 0; kb < 2; ++kb){
      f32x16 S;
#pragma unroll
      for(int r = 0; r < 16; ++r) S[r] = 0.f;
      int krow = kb * 32 + q31;
      __builtin_amdgcn_s_setprio(1);
#pragma unroll
      for(int cst = 0; cst < 8; ++cst){
        uint2v Kf = *reinterpret_cast<const uint2v*>(
            Kc + krow * 128 + ((cst * 16) ^ ((krow & 7) << 4)) + hi * 8);
        S = __builtin_amdgcn_mfma_f32_32x32x16_fp8_fp8(
            __builtin_bit_cast(long, Kf), __builtin_bit_cast(long, Qf[cst]), S, 0, 0, 0);
      }
      __builtin_amdgcn_s_setprio(0);
      float e[16];
#pragma unroll
      for(int r = 0; r < 16; ++r) e[r] = fexp2(S[r] - 4.0f);
#pragma unroll
      for(int r = 0; r < 16; ++r) ps += e[r];
      unsigned u0 = pack4_fp8(e[0],  e[1],  e[2],  e[3]);
      unsigned u1 = pack4_fp8(e[4],  e[5],  e[6],  e[7]);
      unsigned u2 = pack4_fp8(e[8],  e[9],  e[10], e[11]);
      unsigned u3 = pack4_fp8(e[12], e[13], e[14], e[15]);
      asm("v_permlane32_swap_b32 %0, %1" : "+v"(u0), "+v"(u1));
      asm("v_permlane32_swap_b32 %0, %1" : "+v"(u2), "+v"(u3));
      __builtin_amdgcn_s_setprio(1);
#pragma unroll
      for(int cc = 0; cc < 2; ++cc){
        uint2v Pa = cc ? uint2v{u2, u3} : uint2v{u0, u1};
        long Pl = __builtin_bit_cast(long, Pa);
#pragma unroll
        for(int db = 0; db < 4; ++db){
          int d = db * 32 + q31;
          int row = d >> 1;
          int off = (d & 1) * 64 + kb * 32 + cc * 16;
          uint2v Vf = *reinterpret_cast<const uint2v*>(
              Vc + row * 128 + ((off ^ ((row & 7) << 4))) + hi * 8);
          Of[db] = __builtin_amdgcn_mfma_f32_32x32x16_fp8_fp8(
              Pl, __builtin_bit_cast(long, Vf), Of[db], 0, 0, 0);
        }
      }
      __builtin_amdgcn_s_setprio(0);
    }
    __syncthreads();
  }
#undef STAGE

  float pst = ps + __shfl_xor(ps, 32);
  if(hi == 0)
    psums[(size_t)kq * 16384 + n * NP + pbase + q31] = pst;

  float* ow = (float*)(smem + w * 16384);
#pragma unroll
  for(int reg = 0; reg < 16; ++reg){
    int q = (reg & 3) + 8 * (reg >> 2) + 4 * hi;
#pragma unroll
    for(int db = 0; db < 4; ++db)
      ow[q * 128 + db * 32 + q31] = Of[db][reg];
  }
  asm volatile("s_waitcnt lgkmcnt(0)" ::: "memory");
  __builtin_amdgcn_sched_barrier(0);
  short* pr = po + ((size_t)kq * 16384 + n * NP + pbase) * ID;
#pragma unroll
  for(int it = 0; it < 8; ++it){
    int o = it * 1024 + l * 16;
    int q = o >> 8, d0 = (o & 255) >> 1;
    f32x4 va = *reinterpret_cast<const f32x4*>(ow + q * 128 + d0);
    f32x4 vb = *reinterpret_cast<const f32x4*>(ow + q * 128 + d0 + 4);
    uint4v pk4 = { cvtpk(va[0], va[1]), cvtpk(va[2], va[3]),
                   cvtpk(vb[0], vb[1]), cvtpk(vb[2], vb[3]) };
    *reinterpret_cast<short8*>(pr + (size_t)q * ID + d0) = __builtin_bit_cast(short8, pk4);
  }
}

// ---------------- fused: merge 4 k-partials + 1x1 conv + BN + residual ------
__global__ __launch_bounds__(512) void k_outproj(const short* __restrict__ po,
    const float* __restrict__ psums, const short* __restrict__ ow_b,
    const float* __restrict__ bng, const float* __restrict__ bnb,
    const float* __restrict__ bnm, const float* __restrict__ bnv,
    const float* __restrict__ x, float* __restrict__ out){
  __shared__ __align__(16) short XW[64 * 128];
  int b = blockIdx.x;
  int n = b >> 6, pt = b & 63;
  int pg0 = pt * 64;
  int t = threadIdx.x, w = t >> 6, l = t & 63;
  int lr = l & 15, lg = l >> 4;

  {
    int p = t >> 3, i0 = (t & 7) * 16;
    size_t qg = (size_t)n * NP + pg0 + p;
    float den = psums[qg] + psums[16384 + qg] + psums[32768 + qg] + psums[49152 + qg];
    float inv = 1.f / (16.f * den);
    const short* pp = po + qg * ID + i0;
    int key = (p & 15) << 4;
#pragma unroll
    for(int h = 0; h < 2; ++h){
      short8 b0 = *reinterpret_cast<const short8*>(pp + h * 8);
      short8 b1 = *reinterpret_cast<const short8*>(pp + (size_t)16384 * ID + h * 8);
      short8 b2 = *reinterpret_cast<const short8*>(pp + (size_t)32768 * ID + h * 8);
      short8 b3 = *reinterpret_cast<const short8*>(pp + (size_t)49152 * ID + h * 8);
      float f[8];
#pragma unroll
      for(int j = 0; j < 8; ++j)
        f[j] = (bf2f(b0[j]) + bf2f(b1[j]) + bf2f(b2[j]) + bf2f(b3[j])) * inv;
      uint4v pkv = { cvtpk(f[0], f[1]), cvtpk(f[2], f[3]),
                     cvtpk(f[4], f[5]), cvtpk(f[6], f[7]) };
      *reinterpret_cast<short8*>((char*)XW + p * 256 + ((i0 * 2 + h * 16) ^ key)) =
          __builtin_bit_cast(short8, pkv);
    }
  }
  __syncthreads();

  int c0 = w * 32;
  f32x4 acc[2][4];
#pragma unroll
  for(int mf = 0; mf < 2; ++mf)
#pragma unroll
    for(int nf = 0; nf < 4; ++nf) acc[mf][nf] = {0.f,0.f,0.f,0.f};
#pragma unroll
  for(int kk = 0; kk < 4; ++kk){
    short8 Af[2];
#pragma unroll
    for(int mf = 0; mf < 2; ++mf)
      Af[mf] = *reinterpret_cast<const short8*>(ow_b + (size_t)(c0 + mf * 16 + lr) * ID + kk * 32 + lg * 8);
#pragma unroll
    for(int nf = 0; nf < 4; ++nf){
      int prow = nf * 16 + lr;
      short8 Bf = *reinterpret_cast<const short8*>(
          (char*)XW + prow * 256 + ((kk * 64 + lg * 16) ^ ((prow & 15) << 4)));
#pragma unroll
      for(int mf = 0; mf < 2; ++mf)
        acc[mf][nf] = __builtin_amdgcn_mfma_f32_16x16x32_bf16(Af[mf], Bf, acc[mf][nf], 0, 0, 0);
    }
  }

#pragma unroll
  for(int mf = 0; mf < 2; ++mf){
    int cb = c0 + mf * 16 + lg * 4;
    float inv[4], sh[4];
#pragma unroll
    for(int r = 0; r < 4; ++r){
      float iv = bng[cb + r] * rsqrtf(bnv[cb + r] + 1e-5f);
      inv[r] = iv;
      sh[r] = bnb[cb + r] - bnm[cb + r] * iv;
    }
#pragma unroll
    for(int nf = 0; nf < 4; ++nf){
      int p = pg0 + nf * 16 + lr;
#pragma unroll
      for(int r = 0; r < 4; ++r){
        size_t idx = ((size_t)(n * CD + cb + r)) * NP + p;
        out[idx] = acc[mf][nf][r] * inv[r] + sh[r] + x[idx];
      }
    }
  }
}

extern "C" void kernel_launch(void* const* d_in, const int* in_sizes, int n_in,
                              void* d_out, int out_size, void* d_ws, size_t ws_size,
                              hipStream_t stream){
  const float* x    = (const float*)d_in[0];
  const float* g_w  = (const float*)d_in[1];
  const float* g_b  = (const float*)d_in[2];
  const float* th_w = (const float*)d_in[3];
  const float* th_b = (const float*)d_in[4];
  const float* ph_w = (const float*)d_in[5];
  const float* ph_b = (const float*)d_in[6];
  const float* out_w= (const float*)d_in[7];
  const float* bng  = (const float*)d_in[8];
  const float* bnb  = (const float*)d_in[9];
  const float* bnm  = (const float*)d_in[10];
  const float* bnv  = (const float*)d_in[11];
  float* out = (float*)d_out;
  char* ws = (char*)d_ws;

  short* xt          = (short*)(ws);                        // 8 MB  (n,N,C) bf16
  unsigned char* q8  = (unsigned char*)(ws + (size_t)(8u  << 20)); // 2 MB fp8
  unsigned char* k8  = (unsigned char*)(ws + (size_t)(12u << 20)); // 2 MB fp8
  unsigned char* v8  = (unsigned char*)(ws + (size_t)(16u << 20)); // 2 MB fp8 VL
  short* wb          = (short*)(ws + (size_t)(24u << 20));  // 256 KB bf16 weights
  short* po          = (short*)(ws + (size_t)(25u << 20));  // 16 MB partial O bf16
  float* psum        = (float*)(ws + (size_t)(41u << 20));  // 256 KB partial sums

  k_cvtw<<<128, 256, 0, stream>>>(g_w, th_w, ph_w, out_w, wb);
  k_transpose<<<dim3(64, 4, 4), 256, 0, stream>>>(x, xt);
  k_proj<<<256, 512, 0, stream>>>(xt, wb, g_b, th_b, ph_b, q8, k8, v8);
  k_attn<<<512, 256, 0, stream>>>(q8, k8, v8, po, psum);
  k_outproj<<<256, 512, 0, stream>>>(po, psum, wb + 98304, bng, bnb, bnm, bnv, x, out);
}

// Round 14
// 66.493 us; speedup vs baseline: 1.6315x; 1.0220x over previous
//
#include <hip/hip_runtime.h>

typedef short short8 __attribute__((ext_vector_type(8)));
typedef short short4v __attribute__((ext_vector_type(4)));
typedef float f32x4 __attribute__((ext_vector_type(4)));
typedef float f32x16 __attribute__((ext_vector_type(16)));
typedef unsigned int uint4v __attribute__((ext_vector_type(4)));
typedef unsigned int uint2v __attribute__((ext_vector_type(2)));

#define NB 4
#define CD 256
#define ID 128
#define NP 4096

static __device__ __forceinline__ short f2bf(float f){
  unsigned u = __float_as_uint(f);
  u += 0x7FFF + ((u >> 16) & 1);
  return (short)(u >> 16);
}
static __device__ __forceinline__ float bf2f(short s){
  unsigned u = ((unsigned)(unsigned short)s) << 16;
  return __uint_as_float(u);
}
static __device__ __forceinline__ unsigned cvtpk(float lo, float hi){
  unsigned r;
  asm("v_cvt_pk_bf16_f32 %0, %1, %2" : "=v"(r) : "v"(lo), "v"(hi));
  return r;
}
static __device__ __forceinline__ float fexp2(float x){
  float r;
  asm("v_exp_f32 %0, %1" : "=v"(r) : "v"(x));
  return r;
}
static __device__ __forceinline__ unsigned pack4_fp8(float a, float b, float c, float d){
  unsigned lo, hi;
  asm("v_cvt_pk_fp8_f32 %0, %1, %2" : "=v"(lo) : "v"(a), "v"(b));
  asm("v_cvt_pk_fp8_f32 %0, %1, %2" : "=v"(hi) : "v"(c), "v"(d));
  return (lo & 0xffffu) | (hi << 16);
}
static __device__ __forceinline__ unsigned char f2fp8(float v){
  unsigned u;
  asm("v_cvt_pk_fp8_f32 %0, %1, %1" : "=v"(u) : "v"(v));
  return (unsigned char)u;
}

static __device__ __forceinline__ void gload16(const void* g, void* l){
  __builtin_amdgcn_global_load_lds(
      (const __attribute__((address_space(1))) unsigned int*)g,
      (__attribute__((address_space(3))) unsigned int*)l, 16, 0, 0);
}

// ---------------- weights fp32 -> bf16 (g, theta, phi, out concatenated) ----
__global__ __launch_bounds__(256) void k_cvtw(const float* __restrict__ g_w,
    const float* __restrict__ th_w, const float* __restrict__ ph_w,
    const float* __restrict__ out_w, short* __restrict__ wb){
  int idx = (blockIdx.x * 256 + threadIdx.x) * 4;
  const float* s;
  int sel = idx >> 15;
  if(sel == 0) s = g_w; else if(sel == 1) s = th_w; else if(sel == 2) s = ph_w; else s = out_w;
  int off = idx & 32767;
  float4 v = *reinterpret_cast<const float4*>(s + off);
  short4v o = { f2bf(v.x), f2bf(v.y), f2bf(v.z), f2bf(v.w) };
  *reinterpret_cast<short4v*>(wb + idx) = o;
}

// ---------------- x (n,C,N) fp32 -> xt (n,N,C) bf16 -------------------------
__global__ __launch_bounds__(256) void k_transpose(const float* __restrict__ x,
                                                   short* __restrict__ xt){
  __shared__ float T[64][68];
  int n = blockIdx.z, c0 = blockIdx.y * 64, p0 = blockIdx.x * 64;
  int t = threadIdx.x;
  const float* xp = x + ((size_t)(n * CD + c0)) * NP + p0;
#pragma unroll
  for(int it = 0; it < 4; ++it){
    int c = (t >> 4) + it * 16;
    int p = (t & 15) * 4;
    float4 v = *reinterpret_cast<const float4*>(xp + (size_t)c * NP + p);
    T[c][p+0] = v.x; T[c][p+1] = v.y; T[c][p+2] = v.z; T[c][p+3] = v.w;
  }
  __syncthreads();
  short* op = xt + ((size_t)(n * NP + p0)) * CD + c0;
  int p = t >> 2, cc = (t & 3) * 16;
  short8 a, b;
#pragma unroll
  for(int j = 0; j < 8; ++j){ a[j] = f2bf(T[cc + j][p]); b[j] = f2bf(T[cc + 8 + j][p]); }
  *reinterpret_cast<short8*>(op + (size_t)p * CD + cc) = a;
  *reinterpret_cast<short8*>(op + (size_t)p * CD + cc + 8) = b;
}

// ---------------- fused projections (LDS-staged, weight-stationary) ---------
// k8 stored with INTERLEAVED columns: c' = (cst>>1)*32 + hi*16 + (cst&1)*8 + j
// (so attention can b128-read a cst-PAIR conflict-free). v8 stored pre-tiled
// to the attention LDS order: [panel][kb][hi][d][cc*8+j] (linear staging).
__global__ __launch_bounds__(512) void k_proj(const short* __restrict__ xt,
    const short* __restrict__ wb, const float* __restrict__ g_b,
    const float* __restrict__ th_b, const float* __restrict__ ph_b,
    unsigned char* __restrict__ q8, unsigned char* __restrict__ k8,
    unsigned char* __restrict__ v8){
  __shared__ __align__(16) char XT[32768];
  int b = blockIdx.x;
  int n = b >> 6, pt = b & 63;
  int pb0 = pt * 64;
  int t = threadIdx.x, w = t >> 6, l = t & 63;
  int lr = l & 15, lg = l >> 4;
  int i0 = w * 16;

  const char* xg = (const char*)(xt + ((size_t)(n * NP + pb0)) * CD);
#pragma unroll
  for(int i_ = 0; i_ < 4; ++i_){
    int dd = t * 16 + i_ * 8192;
    int row = dd >> 9;
    int sz = (dd & ~511) | ((dd & 511) ^ ((row & 15) << 4));
    gload16(xg + sz, XT + dd);
  }

  const short* gww = wb;
  const short* thw = wb + 32768;
  const short* phw = wb + 65536;
  short8 Wt[8], Wp[8], Wg[8];
#pragma unroll
  for(int kk = 0; kk < 8; ++kk){
    size_t wo = (size_t)(i0 + lr) * CD + kk * 32 + lg * 8;
    Wt[kk] = *reinterpret_cast<const short8*>(thw + wo);
    Wp[kk] = *reinterpret_cast<const short8*>(phw + wo);
    Wg[kk] = *reinterpret_cast<const short8*>(gww + wo);
  }
  float bt = th_b[i0 + lr];
  float bp = ph_b[i0 + lr];
  // interleaved column index for k8
  int ik = i0 + lr;
  int ip = (ik & 7) | (((ik >> 4) & 1) << 3) | (((ik >> 3) & 1) << 4) | ((ik >> 5) << 5);
  float gb[4];
#pragma unroll
  for(int r = 0; r < 4; ++r) gb[r] = g_b[i0 + lg * 4 + r];

  __syncthreads();

  size_t vbase = ((size_t)n * 64 + pt) * 8192;
#pragma unroll
  for(int psub = 0; psub < 4; ++psub){
    int prow = psub * 16 + lr;
    short8 X[8];
#pragma unroll
    for(int kk = 0; kk < 8; ++kk)
      X[kk] = *reinterpret_cast<const short8*>(
          XT + prow * 512 + ((kk * 64 + lg * 16) ^ ((prow & 15) << 4)));
    f32x4 aT = {0.f,0.f,0.f,0.f}, aP = {0.f,0.f,0.f,0.f}, aG = {0.f,0.f,0.f,0.f};
#pragma unroll
    for(int kk = 0; kk < 8; ++kk){
      aT = __builtin_amdgcn_mfma_f32_16x16x32_bf16(X[kk], Wt[kk], aT, 0, 0, 0);
      aP = __builtin_amdgcn_mfma_f32_16x16x32_bf16(X[kk], Wp[kk], aP, 0, 0, 0);
      aG = __builtin_amdgcn_mfma_f32_16x16x32_bf16(Wg[kk], X[kk], aG, 0, 0, 0);
    }
#pragma unroll
    for(int r = 0; r < 4; ++r){
      size_t row = (size_t)(n * NP + pb0 + psub * 16 + lg * 4 + r);
      q8[row * ID + i0 + lr] = f2fp8((aT[r] + bt) * 1.44269504f);  // log2(e)
      k8[row * ID + ip]      = f2fp8(aP[r] + bp);
    }
    // v8: [kb=psub>>1][hi=lr>>3][d=ii][ (cc=psub&1)*8 + (j=lr&7) ]
#pragma unroll
    for(int r = 0; r < 4; ++r){
      int ii = i0 + lg * 4 + r;
      v8[vbase + (psub >> 1) * 4096 + ((lr >> 3) & 1) * 2048 + ii * 16
               + (psub & 1) * 8 + (lr & 7)] = f2fp8(aG[r] + gb[r]);
    }
  }
}

// ---------------- flash attention, fp8, swapped-QK 32x32, in-reg P ----------
// R10 schedule; NEW conflict-free LDS tiles:
//   K: [cp][hi][krow][16B] (cst-pair b128 reads, 32 lanes consecutive)
//   V: [kb][hi][d][16B]    (cc-pair b128 reads, linear staging)
__global__ __launch_bounds__(256, 2) void k_attn(const unsigned char* __restrict__ q8,
    const unsigned char* __restrict__ k8, const unsigned char* __restrict__ v8,
    short* __restrict__ po, float* __restrict__ psums){
  __shared__ __align__(16) char smem[65536];
  int b = blockIdx.x;
  int xcd = b & 7;
  int n = xcd >> 1;
  int kq = ((xcd & 1) << 1) | ((b >> 3) & 1);
  int qtl = b >> 4;
  int t = threadIdx.x, w = t >> 6, l = t & 63;
  int q31 = l & 31, hi = l >> 5;
  int pbase = qtl * 128 + w * 32;

  const char* kpanel = (const char*)k8 + ((size_t)(n * NP + kq * 1024)) * ID;
  const char* vpanel = (const char*)v8 + ((size_t)n * 64 + kq * 16) * 8192;
  const char* qbase  = (const char*)q8 + ((size_t)(n * NP + pbase)) * ID;

  uint2v Qf[8];
#pragma unroll
  for(int cst = 0; cst < 8; ++cst)
    Qf[cst] = *reinterpret_cast<const uint2v*>(qbase + q31 * 128 + cst * 16 + hi * 8);

  f32x16 Of[4];
#pragma unroll
  for(int db = 0; db < 4; ++db)
#pragma unroll
    for(int r = 0; r < 16; ++r) Of[db][r] = 0.f;
  float ps = 0.f;

  // K source granule permute: LDS chunk dd -> cp=dd>>11, hi=(dd>>10)&1,
  // krow=(dd>>4)&63; source (interleaved row-major) = krow*128+cp*32+hi*16.
#define STAGE(cb, kt_) do { \
    const char* kg_ = kpanel + (size_t)(kt_) * 8192; \
    const char* vg_ = vpanel + (size_t)(kt_) * 8192; \
    char* kld_ = smem + (cb) * 8192; \
    char* vld_ = smem + 16384 + (cb) * 8192; \
    _Pragma("unroll") \
    for(int i_ = 0; i_ < 2; ++i_){ \
      int dd = t * 16 + i_ * 4096; \
      int ks = (((dd >> 4) & 63) << 7) | ((dd >> 11) << 5) | (((dd >> 10) & 1) << 4); \
      gload16(kg_ + ks, kld_ + dd); \
      gload16(vg_ + dd, vld_ + dd); \
    } \
  } while(0)

  STAGE(0, 0);
  __syncthreads();

#pragma unroll 2
  for(int kt = 0; kt < 16; ++kt){
    const int pb = kt & 1;
    if(kt + 1 < 16) STAGE(pb ^ 1, kt + 1);
    const char* Kc = smem + pb * 8192;
    const char* Vc = smem + 16384 + pb * 8192;
#pragma unroll
    for(int kb = 0; kb < 2; ++kb){
      f32x16 S;
#pragma unroll
      for(int r = 0; r < 16; ++r) S[r] = 0.f;
      int krow = kb * 32 + q31;
      __builtin_amdgcn_s_setprio(1);
#pragma unroll
      for(int cp = 0; cp < 4; ++cp){
        uint4v Kp = *reinterpret_cast<const uint4v*>(
            Kc + cp * 2048 + hi * 1024 + krow * 16);
        uint2v Ka = { Kp[0], Kp[1] };
        uint2v Kb2 = { Kp[2], Kp[3] };
        S = __builtin_amdgcn_mfma_f32_32x32x16_fp8_fp8(
            __builtin_bit_cast(long, Ka), __builtin_bit_cast(long, Qf[2*cp]), S, 0, 0, 0);
        S = __builtin_amdgcn_mfma_f32_32x32x16_fp8_fp8(
            __builtin_bit_cast(long, Kb2), __builtin_bit_cast(long, Qf[2*cp+1]), S, 0, 0, 0);
      }
      __builtin_amdgcn_s_setprio(0);
      float e[16];
#pragma unroll
      for(int r = 0; r < 16; ++r) e[r] = fexp2(S[r] - 4.0f);
#pragma unroll
      for(int r = 0; r < 16; ++r) ps += e[r];
      unsigned u0 = pack4_fp8(e[0],  e[1],  e[2],  e[3]);
      unsigned u1 = pack4_fp8(e[4],  e[5],  e[6],  e[7]);
      unsigned u2 = pack4_fp8(e[8],  e[9],  e[10], e[11]);
      unsigned u3 = pack4_fp8(e[12], e[13], e[14], e[15]);
      asm("v_permlane32_swap_b32 %0, %1" : "+v"(u0), "+v"(u1));
      asm("v_permlane32_swap_b32 %0, %1" : "+v"(u2), "+v"(u3));
      long P0 = __builtin_bit_cast(long, uint2v{u0, u1});   // k chunk cc=0
      long P1 = __builtin_bit_cast(long, uint2v{u2, u3});   // k chunk cc=1
      __builtin_amdgcn_s_setprio(1);
#pragma unroll
      for(int db = 0; db < 4; ++db){
        int d = db * 32 + q31;
        uint4v Vp = *reinterpret_cast<const uint4v*>(
            Vc + kb * 4096 + hi * 2048 + d * 16);
        uint2v Va = { Vp[0], Vp[1] };
        uint2v Vb = { Vp[2], Vp[3] };
        Of[db] = __builtin_amdgcn_mfma_f32_32x32x16_fp8_fp8(
            P0, __builtin_bit_cast(long, Va), Of[db], 0, 0, 0);
        Of[db] = __builtin_amdgcn_mfma_f32_32x32x16_fp8_fp8(
            P1, __builtin_bit_cast(long, Vb), Of[db], 0, 0, 0);
      }
      __builtin_amdgcn_s_setprio(0);
    }
    __syncthreads();
  }
#undef STAGE

  float pst = ps + __shfl_xor(ps, 32);
  if(hi == 0)
    psums[(size_t)kq * 16384 + n * NP + pbase + q31] = pst;

  float* ow = (float*)(smem + w * 16384);
#pragma unroll
  for(int reg = 0; reg < 16; ++reg){
    int q = (reg & 3) + 8 * (reg >> 2) + 4 * hi;
#pragma unroll
    for(int db = 0; db < 4; ++db)
      ow[q * 128 + db * 32 + q31] = Of[db][reg];
  }
  asm volatile("s_waitcnt lgkmcnt(0)" ::: "memory");
  __builtin_amdgcn_sched_barrier(0);
  short* pr = po + ((size_t)kq * 16384 + n * NP + pbase) * ID;
#pragma unroll
  for(int it = 0; it < 8; ++it){
    int o = it * 1024 + l * 16;
    int q = o >> 8, d0 = (o & 255) >> 1;
    f32x4 va = *reinterpret_cast<const f32x4*>(ow + q * 128 + d0);
    f32x4 vb = *reinterpret_cast<const f32x4*>(ow + q * 128 + d0 + 4);
    uint4v pk4 = { cvtpk(va[0], va[1]), cvtpk(va[2], va[3]),
                   cvtpk(vb[0], vb[1]), cvtpk(vb[2], vb[3]) };
    *reinterpret_cast<short8*>(pr + (size_t)q * ID + d0) = __builtin_bit_cast(short8, pk4);
  }
}

// ---------------- fused: merge 4 k-partials + 1x1 conv + BN + residual ------
__global__ __launch_bounds__(512) void k_outproj(const short* __restrict__ po,
    const float* __restrict__ psums, const short* __restrict__ ow_b,
    const float* __restrict__ bng, const float* __restrict__ bnb,
    const float* __restrict__ bnm, const float* __restrict__ bnv,
    const float* __restrict__ x, float* __restrict__ out){
  __shared__ __align__(16) short XW[64 * 128];
  int b = blockIdx.x;
  int n = b >> 6, pt = b & 63;
  int pg0 = pt * 64;
  int t = threadIdx.x, w = t >> 6, l = t & 63;
  int lr = l & 15, lg = l >> 4;

  {
    int p = t >> 3, i0 = (t & 7) * 16;
    size_t qg = (size_t)n * NP + pg0 + p;
    float den = psums[qg] + psums[16384 + qg] + psums[32768 + qg] + psums[49152 + qg];
    float inv = 1.f / (16.f * den);
    const short* pp = po + qg * ID + i0;
    int key = (p & 15) << 4;
#pragma unroll
    for(int h = 0; h < 2; ++h){
      short8 b0 = *reinterpret_cast<const short8*>(pp + h * 8);
      short8 b1 = *reinterpret_cast<const short8*>(pp + (size_t)16384 * ID + h * 8);
      short8 b2 = *reinterpret_cast<const short8*>(pp + (size_t)32768 * ID + h * 8);
      short8 b3 = *reinterpret_cast<const short8*>(pp + (size_t)49152 * ID + h * 8);
      float f[8];
#pragma unroll
      for(int j = 0; j < 8; ++j)
        f[j] = (bf2f(b0[j]) + bf2f(b1[j]) + bf2f(b2[j]) + bf2f(b3[j])) * inv;
      uint4v pkv = { cvtpk(f[0], f[1]), cvtpk(f[2], f[3]),
                     cvtpk(f[4], f[5]), cvtpk(f[6], f[7]) };
      *reinterpret_cast<short8*>((char*)XW + p * 256 + ((i0 * 2 + h * 16) ^ key)) =
          __builtin_bit_cast(short8, pkv);
    }
  }
  __syncthreads();

  int c0 = w * 32;
  f32x4 acc[2][4];
#pragma unroll
  for(int mf = 0; mf < 2; ++mf)
#pragma unroll
    for(int nf = 0; nf < 4; ++nf) acc[mf][nf] = {0.f,0.f,0.f,0.f};
#pragma unroll
  for(int kk = 0; kk < 4; ++kk){
    short8 Af[2];
#pragma unroll
    for(int mf = 0; mf < 2; ++mf)
      Af[mf] = *reinterpret_cast<const short8*>(ow_b + (size_t)(c0 + mf * 16 + lr) * ID + kk * 32 + lg * 8);
#pragma unroll
    for(int nf = 0; nf < 4; ++nf){
      int prow = nf * 16 + lr;
      short8 Bf = *reinterpret_cast<const short8*>(
          (char*)XW + prow * 256 + ((kk * 64 + lg * 16) ^ ((prow & 15) << 4)));
#pragma unroll
      for(int mf = 0; mf < 2; ++mf)
        acc[mf][nf] = __builtin_amdgcn_mfma_f32_16x16x32_bf16(Af[mf], Bf, acc[mf][nf], 0, 0, 0);
    }
  }

#pragma unroll
  for(int mf = 0; mf < 2; ++mf){
    int cb = c0 + mf * 16 + lg * 4;
    float inv[4], sh[4];
#pragma unroll
    for(int r = 0; r < 4; ++r){
      float iv = bng[cb + r] * rsqrtf(bnv[cb + r] + 1e-5f);
      inv[r] = iv;
      sh[r] = bnb[cb + r] - bnm[cb + r] * iv;
    }
#pragma unroll
    for(int nf = 0; nf < 4; ++nf){
      int p = pg0 + nf * 16 + lr;
#pragma unroll
      for(int r = 0; r < 4; ++r){
        size_t idx = ((size_t)(n * CD + cb + r)) * NP + p;
        out[idx] = acc[mf][nf][r] * inv[r] + sh[r] + x[idx];
      }
    }
  }
}

extern "C" void kernel_launch(void* const* d_in, const int* in_sizes, int n_in,
                              void* d_out, int out_size, void* d_ws, size_t ws_size,
                              hipStream_t stream){
  const float* x    = (const float*)d_in[0];
  const float* g_w  = (const float*)d_in[1];
  const float* g_b  = (const float*)d_in[2];
  const float* th_w = (const float*)d_in[3];
  const float* th_b = (const float*)d_in[4];
  const float* ph_w = (const float*)d_in[5];
  const float* ph_b = (const float*)d_in[6];
  const float* out_w= (const float*)d_in[7];
  const float* bng  = (const float*)d_in[8];
  const float* bnb  = (const float*)d_in[9];
  const float* bnm  = (const float*)d_in[10];
  const float* bnv  = (const float*)d_in[11];
  float* out = (float*)d_out;
  char* ws = (char*)d_ws;

  short* xt          = (short*)(ws);                        // 8 MB  (n,N,C) bf16
  unsigned char* q8  = (unsigned char*)(ws + (size_t)(8u  << 20)); // 2 MB fp8
  unsigned char* k8  = (unsigned char*)(ws + (size_t)(12u << 20)); // 2 MB fp8 interleaved
  unsigned char* v8  = (unsigned char*)(ws + (size_t)(16u << 20)); // 2 MB fp8 tiled
  short* wb          = (short*)(ws + (size_t)(24u << 20));  // 256 KB bf16 weights
  short* po          = (short*)(ws + (size_t)(25u << 20));  // 16 MB partial O bf16
  float* psum        = (float*)(ws + (size_t)(41u << 20));  // 256 KB partial sums

  k_cvtw<<<128, 256, 0, stream>>>(g_w, th_w, ph_w, out_w, wb);
  k_transpose<<<dim3(64, 4, 4), 256, 0, stream>>>(x, xt);
  k_proj<<<256, 512, 0, stream>>>(xt, wb, g_b, th_b, ph_b, q8, k8, v8);
  k_attn<<<512, 256, 0, stream>>>(q8, k8, v8, po, psum);
  k_outproj<<<256, 512, 0, stream>>>(po, psum, wb + 98304, bng, bnb, bnm, bnv, x, out);
}

// Round 15
// 64.526 us; speedup vs baseline: 1.6812x; 1.0305x over previous
//
#include <hip/hip_runtime.h>

typedef short short8 __attribute__((ext_vector_type(8)));
typedef short short4v __attribute__((ext_vector_type(4)));
typedef float f32x4 __attribute__((ext_vector_type(4)));
typedef float f32x16 __attribute__((ext_vector_type(16)));
typedef unsigned int uint4v __attribute__((ext_vector_type(4)));
typedef unsigned int uint2v __attribute__((ext_vector_type(2)));

#define NB 4
#define CD 256
#define ID 128
#define NP 4096

static __device__ __forceinline__ short f2bf(float f){
  unsigned u = __float_as_uint(f);
  u += 0x7FFF + ((u >> 16) & 1);
  return (short)(u >> 16);
}
static __device__ __forceinline__ float bf2f(short s){
  unsigned u = ((unsigned)(unsigned short)s) << 16;
  return __uint_as_float(u);
}
static __device__ __forceinline__ unsigned cvtpk(float lo, float hi){
  unsigned r;
  asm("v_cvt_pk_bf16_f32 %0, %1, %2" : "=v"(r) : "v"(lo), "v"(hi));
  return r;
}
static __device__ __forceinline__ float fexp2(float x){
  float r;
  asm("v_exp_f32 %0, %1" : "=v"(r) : "v"(x));
  return r;
}
static __device__ __forceinline__ unsigned pack4_fp8(float a, float b, float c, float d){
  unsigned lo, hi;
  asm("v_cvt_pk_fp8_f32 %0, %1, %2" : "=v"(lo) : "v"(a), "v"(b));
  asm("v_cvt_pk_fp8_f32 %0, %1, %2" : "=v"(hi) : "v"(c), "v"(d));
  return (lo & 0xffffu) | (hi << 16);
}
static __device__ __forceinline__ unsigned char f2fp8(float v){
  unsigned u;
  asm("v_cvt_pk_fp8_f32 %0, %1, %1" : "=v"(u) : "v"(v));
  return (unsigned char)u;
}

static __device__ __forceinline__ void gload16(const void* g, void* l){
  __builtin_amdgcn_global_load_lds(
      (const __attribute__((address_space(1))) unsigned int*)g,
      (__attribute__((address_space(3))) unsigned int*)l, 16, 0, 0);
}

// ---------------- weights fp32 -> bf16 (g, theta, phi, out concatenated) ----
__global__ __launch_bounds__(256) void k_cvtw(const float* __restrict__ g_w,
    const float* __restrict__ th_w, const float* __restrict__ ph_w,
    const float* __restrict__ out_w, short* __restrict__ wb){
  int idx = (blockIdx.x * 256 + threadIdx.x) * 4;
  const float* s;
  int sel = idx >> 15;
  if(sel == 0) s = g_w; else if(sel == 1) s = th_w; else if(sel == 2) s = ph_w; else s = out_w;
  int off = idx & 32767;
  float4 v = *reinterpret_cast<const float4*>(s + off);
  short4v o = { f2bf(v.x), f2bf(v.y), f2bf(v.z), f2bf(v.w) };
  *reinterpret_cast<short4v*>(wb + idx) = o;
}

// ---------------- fused transpose + projections (LDS-staged) ----------------
// Grid 256 = n(4) x ptile(64 rows); 512 thr = 8 waves. Stages RAW x fp32
// [256c][64p] (64KB, linear coalesced global_load_lds), converts in-LDS to
// the bf16 transposed tile [64p][512B swizzled], then weight-stationary
// MFMAs produce q8/k8 (interleaved cols) and v8 (attention-tiled), all fp8.
__global__ __launch_bounds__(512) void k_proj(const float* __restrict__ x,
    const short* __restrict__ wb, const float* __restrict__ g_b,
    const float* __restrict__ th_b, const float* __restrict__ ph_b,
    unsigned char* __restrict__ q8, unsigned char* __restrict__ k8,
    unsigned char* __restrict__ v8){
  __shared__ __align__(16) char smem[98304];   // XF fp32 64KB | XT bf16 32KB
  char* XT = smem + 65536;
  int b = blockIdx.x;
  int n = b >> 6, pt = b & 63;
  int pb0 = pt * 64;
  int t = threadIdx.x, w = t >> 6, l = t & 63;
  int lr = l & 15, lg = l >> 4;
  int i0 = w * 16;

  // stage x tile: source row c = 256B at x[n][c][pb0..pb0+63]
  const char* xg = (const char*)(x + ((size_t)n * CD) * NP + pb0);
#pragma unroll
  for(int i_ = 0; i_ < 8; ++i_){
    int dd = t * 16 + i_ * 8192;
    gload16(xg + (size_t)(dd >> 8) * 16384 + (dd & 255), smem + dd);
  }

  // stationary weight fragments (dual-role) — overlap with staging
  const short* gww = wb;
  const short* thw = wb + 32768;
  const short* phw = wb + 65536;
  short8 Wt[8], Wp[8], Wg[8];
#pragma unroll
  for(int kk = 0; kk < 8; ++kk){
    size_t wo = (size_t)(i0 + lr) * CD + kk * 32 + lg * 8;
    Wt[kk] = *reinterpret_cast<const short8*>(thw + wo);
    Wp[kk] = *reinterpret_cast<const short8*>(phw + wo);
    Wg[kk] = *reinterpret_cast<const short8*>(gww + wo);
  }
  float bt = th_b[i0 + lr];
  float bp = ph_b[i0 + lr];
  int ik = i0 + lr;   // interleaved column index for k8
  int ip = (ik & 7) | (((ik >> 4) & 1) << 3) | (((ik >> 3) & 1) << 4) | ((ik >> 5) << 5);
  float gb[4];
#pragma unroll
  for(int r = 0; r < 4; ++r) gb[r] = g_b[i0 + lg * 4 + r];

  __syncthreads();   // staged XF complete (barrier drains vmcnt)

  // convert fp32 [c][p] -> bf16 XT [p][c*2 ^ key]; wave covers all 64 p,
  // each lane handles 16 c-pairs (4 x b128 swizzled writes, 2-way banks).
  {
    int p = l;
    const float* src = (const float*)smem;
    int key = (p & 15) << 4;
#pragma unroll
    for(int jj = 0; jj < 4; ++jj){
      unsigned pk4v[4];
#pragma unroll
      for(int q = 0; q < 4; ++q){
        int cp2 = w * 16 + jj * 4 + q;
        float f0 = src[(2 * cp2) * 64 + p];
        float f1 = src[(2 * cp2 + 1) * 64 + p];
        pk4v[q] = cvtpk(f0, f1);
      }
      uint4v v4 = { pk4v[0], pk4v[1], pk4v[2], pk4v[3] };
      *reinterpret_cast<uint4v*>(XT + p * 512 + ((w * 64 + jj * 16) ^ key)) = v4;
    }
  }
  __syncthreads();

  size_t vbase = ((size_t)n * 64 + pt) * 8192;
#pragma unroll
  for(int psub = 0; psub < 4; ++psub){
    int prow = psub * 16 + lr;
    short8 X[8];
#pragma unroll
    for(int kk = 0; kk < 8; ++kk)
      X[kk] = *reinterpret_cast<const short8*>(
          XT + prow * 512 + ((kk * 64 + lg * 16) ^ ((prow & 15) << 4)));
    f32x4 aT = {0.f,0.f,0.f,0.f}, aP = {0.f,0.f,0.f,0.f}, aG = {0.f,0.f,0.f,0.f};
#pragma unroll
    for(int kk = 0; kk < 8; ++kk){
      aT = __builtin_amdgcn_mfma_f32_16x16x32_bf16(X[kk], Wt[kk], aT, 0, 0, 0);
      aP = __builtin_amdgcn_mfma_f32_16x16x32_bf16(X[kk], Wp[kk], aP, 0, 0, 0);
      aG = __builtin_amdgcn_mfma_f32_16x16x32_bf16(Wg[kk], X[kk], aG, 0, 0, 0);
    }
#pragma unroll
    for(int r = 0; r < 4; ++r){
      size_t row = (size_t)(n * NP + pb0 + psub * 16 + lg * 4 + r);
      q8[row * ID + i0 + lr] = f2fp8((aT[r] + bt) * 1.44269504f);  // log2(e)
      k8[row * ID + ip]      = f2fp8(aP[r] + bp);
    }
#pragma unroll
    for(int r = 0; r < 4; ++r){
      int ii = i0 + lg * 4 + r;
      v8[vbase + (psub >> 1) * 4096 + ((lr >> 3) & 1) * 2048 + ii * 16
               + (psub & 1) * 8 + (lr & 7)] = f2fp8(aG[r] + gb[r]);
    }
  }
}

// ---------------- flash attention, fp8, swapped-QK 32x32, in-reg P ----------
// R10 schedule + conflict-free K/V tiles (R13) + SPLIT QK accumulator
// (Sa/Sb: two independent 4-MFMA chains instead of one 8-chain).
__global__ __launch_bounds__(256, 2) void k_attn(const unsigned char* __restrict__ q8,
    const unsigned char* __restrict__ k8, const unsigned char* __restrict__ v8,
    short* __restrict__ po, float* __restrict__ psums){
  __shared__ __align__(16) char smem[65536];
  int b = blockIdx.x;
  int xcd = b & 7;
  int n = xcd >> 1;
  int kq = ((xcd & 1) << 1) | ((b >> 3) & 1);
  int qtl = b >> 4;
  int t = threadIdx.x, w = t >> 6, l = t & 63;
  int q31 = l & 31, hi = l >> 5;
  int pbase = qtl * 128 + w * 32;

  const char* kpanel = (const char*)k8 + ((size_t)(n * NP + kq * 1024)) * ID;
  const char* vpanel = (const char*)v8 + ((size_t)n * 64 + kq * 16) * 8192;
  const char* qbase  = (const char*)q8 + ((size_t)(n * NP + pbase)) * ID;

  uint2v Qf[8];
#pragma unroll
  for(int cst = 0; cst < 8; ++cst)
    Qf[cst] = *reinterpret_cast<const uint2v*>(qbase + q31 * 128 + cst * 16 + hi * 8);

  f32x16 Of[4];
#pragma unroll
  for(int db = 0; db < 4; ++db)
#pragma unroll
    for(int r = 0; r < 16; ++r) Of[db][r] = 0.f;
  float ps = 0.f;

#define STAGE(cb, kt_) do { \
    const char* kg_ = kpanel + (size_t)(kt_) * 8192; \
    const char* vg_ = vpanel + (size_t)(kt_) * 8192; \
    char* kld_ = smem + (cb) * 8192; \
    char* vld_ = smem + 16384 + (cb) * 8192; \
    _Pragma("unroll") \
    for(int i_ = 0; i_ < 2; ++i_){ \
      int dd = t * 16 + i_ * 4096; \
      int ks = (((dd >> 4) & 63) << 7) | ((dd >> 11) << 5) | (((dd >> 10) & 1) << 4); \
      gload16(kg_ + ks, kld_ + dd); \
      gload16(vg_ + dd, vld_ + dd); \
    } \
  } while(0)

  STAGE(0, 0);
  __syncthreads();

#pragma unroll 2
  for(int kt = 0; kt < 16; ++kt){
    const int pb = kt & 1;
    if(kt + 1 < 16) STAGE(pb ^ 1, kt + 1);
    const char* Kc = smem + pb * 8192;
    const char* Vc = smem + 16384 + pb * 8192;
#pragma unroll
    for(int kb = 0; kb < 2; ++kb){
      // two independent QK chains (halved dependency latency)
      f32x16 Sa, Sb;
#pragma unroll
      for(int r = 0; r < 16; ++r){ Sa[r] = 0.f; Sb[r] = 0.f; }
      int krow = kb * 32 + q31;
      __builtin_amdgcn_s_setprio(1);
#pragma unroll
      for(int cp = 0; cp < 4; ++cp){
        uint4v Kp = *reinterpret_cast<const uint4v*>(
            Kc + cp * 2048 + hi * 1024 + krow * 16);
        uint2v Ka = { Kp[0], Kp[1] };
        uint2v Kb2 = { Kp[2], Kp[3] };
        Sa = __builtin_amdgcn_mfma_f32_32x32x16_fp8_fp8(
            __builtin_bit_cast(long, Ka), __builtin_bit_cast(long, Qf[2*cp]), Sa, 0, 0, 0);
        Sb = __builtin_amdgcn_mfma_f32_32x32x16_fp8_fp8(
            __builtin_bit_cast(long, Kb2), __builtin_bit_cast(long, Qf[2*cp+1]), Sb, 0, 0, 0);
      }
      __builtin_amdgcn_s_setprio(0);
      float e[16];
#pragma unroll
      for(int r = 0; r < 16; ++r) e[r] = fexp2(Sa[r] + Sb[r] - 4.0f);
#pragma unroll
      for(int r = 0; r < 16; ++r) ps += e[r];
      unsigned u0 = pack4_fp8(e[0],  e[1],  e[2],  e[3]);
      unsigned u1 = pack4_fp8(e[4],  e[5],  e[6],  e[7]);
      unsigned u2 = pack4_fp8(e[8],  e[9],  e[10], e[11]);
      unsigned u3 = pack4_fp8(e[12], e[13], e[14], e[15]);
      asm("v_permlane32_swap_b32 %0, %1" : "+v"(u0), "+v"(u1));
      asm("v_permlane32_swap_b32 %0, %1" : "+v"(u2), "+v"(u3));
      long P0 = __builtin_bit_cast(long, uint2v{u0, u1});
      long P1 = __builtin_bit_cast(long, uint2v{u2, u3});
      __builtin_amdgcn_s_setprio(1);
#pragma unroll
      for(int db = 0; db < 4; ++db){
        int d = db * 32 + q31;
        uint4v Vp = *reinterpret_cast<const uint4v*>(
            Vc + kb * 4096 + hi * 2048 + d * 16);
        uint2v Va = { Vp[0], Vp[1] };
        uint2v Vb = { Vp[2], Vp[3] };
        Of[db] = __builtin_amdgcn_mfma_f32_32x32x16_fp8_fp8(
            P0, __builtin_bit_cast(long, Va), Of[db], 0, 0, 0);
        Of[db] = __builtin_amdgcn_mfma_f32_32x32x16_fp8_fp8(
            P1, __builtin_bit_cast(long, Vb), Of[db], 0, 0, 0);
      }
      __builtin_amdgcn_s_setprio(0);
    }
    __syncthreads();
  }
#undef STAGE

  float pst = ps + __shfl_xor(ps, 32);
  if(hi == 0)
    psums[(size_t)kq * 16384 + n * NP + pbase + q31] = pst;

  float* ow = (float*)(smem + w * 16384);
#pragma unroll
  for(int reg = 0; reg < 16; ++reg){
    int q = (reg & 3) + 8 * (reg >> 2) + 4 * hi;
#pragma unroll
    for(int db = 0; db < 4; ++db)
      ow[q * 128 + db * 32 + q31] = Of[db][reg];
  }
  asm volatile("s_waitcnt lgkmcnt(0)" ::: "memory");
  __builtin_amdgcn_sched_barrier(0);
  short* pr = po + ((size_t)kq * 16384 + n * NP + pbase) * ID;
#pragma unroll
  for(int it = 0; it < 8; ++it){
    int o = it * 1024 + l * 16;
    int q = o >> 8, d0 = (o & 255) >> 1;
    f32x4 va = *reinterpret_cast<const f32x4*>(ow + q * 128 + d0);
    f32x4 vb = *reinterpret_cast<const f32x4*>(ow + q * 128 + d0 + 4);
    uint4v pk4 = { cvtpk(va[0], va[1]), cvtpk(va[2], va[3]),
                   cvtpk(vb[0], vb[1]), cvtpk(vb[2], vb[3]) };
    *reinterpret_cast<short8*>(pr + (size_t)q * ID + d0) = __builtin_bit_cast(short8, pk4);
  }
}

// ---------------- fused: merge 4 k-partials + 1x1 conv + BN + residual ------
__global__ __launch_bounds__(512) void k_outproj(const short* __restrict__ po,
    const float* __restrict__ psums, const short* __restrict__ ow_b,
    const float* __restrict__ bng, const float* __restrict__ bnb,
    const float* __restrict__ bnm, const float* __restrict__ bnv,
    const float* __restrict__ x, float* __restrict__ out){
  __shared__ __align__(16) short XW[64 * 128];
  int b = blockIdx.x;
  int n = b >> 6, pt = b & 63;
  int pg0 = pt * 64;
  int t = threadIdx.x, w = t >> 6, l = t & 63;
  int lr = l & 15, lg = l >> 4;

  {
    int p = t >> 3, i0 = (t & 7) * 16;
    size_t qg = (size_t)n * NP + pg0 + p;
    float den = psums[qg] + psums[16384 + qg] + psums[32768 + qg] + psums[49152 + qg];
    float inv = 1.f / (16.f * den);
    const short* pp = po + qg * ID + i0;
    int key = (p & 15) << 4;
#pragma unroll
    for(int h = 0; h < 2; ++h){
      short8 b0 = *reinterpret_cast<const short8*>(pp + h * 8);
      short8 b1 = *reinterpret_cast<const short8*>(pp + (size_t)16384 * ID + h * 8);
      short8 b2 = *reinterpret_cast<const short8*>(pp + (size_t)32768 * ID + h * 8);
      short8 b3 = *reinterpret_cast<const short8*>(pp + (size_t)49152 * ID + h * 8);
      float f[8];
#pragma unroll
      for(int j = 0; j < 8; ++j)
        f[j] = (bf2f(b0[j]) + bf2f(b1[j]) + bf2f(b2[j]) + bf2f(b3[j])) * inv;
      uint4v pkv = { cvtpk(f[0], f[1]), cvtpk(f[2], f[3]),
                     cvtpk(f[4], f[5]), cvtpk(f[6], f[7]) };
      *reinterpret_cast<short8*>((char*)XW + p * 256 + ((i0 * 2 + h * 16) ^ key)) =
          __builtin_bit_cast(short8, pkv);
    }
  }
  __syncthreads();

  int c0 = w * 32;
  f32x4 acc[2][4];
#pragma unroll
  for(int mf = 0; mf < 2; ++mf)
#pragma unroll
    for(int nf = 0; nf < 4; ++nf) acc[mf][nf] = {0.f,0.f,0.f,0.f};
#pragma unroll
  for(int kk = 0; kk < 4; ++kk){
    short8 Af[2];
#pragma unroll
    for(int mf = 0; mf < 2; ++mf)
      Af[mf] = *reinterpret_cast<const short8*>(ow_b + (size_t)(c0 + mf * 16 + lr) * ID + kk * 32 + lg * 8);
#pragma unroll
    for(int nf = 0; nf < 4; ++nf){
      int prow = nf * 16 + lr;
      short8 Bf = *reinterpret_cast<const short8*>(
          (char*)XW + prow * 256 + ((kk * 64 + lg * 16) ^ ((prow & 15) << 4)));
#pragma unroll
      for(int mf = 0; mf < 2; ++mf)
        acc[mf][nf] = __builtin_amdgcn_mfma_f32_16x16x32_bf16(Af[mf], Bf, acc[mf][nf], 0, 0, 0);
    }
  }

#pragma unroll
  for(int mf = 0; mf < 2; ++mf){
    int cb = c0 + mf * 16 + lg * 4;
    float inv[4], sh[4];
#pragma unroll
    for(int r = 0; r < 4; ++r){
      float iv = bng[cb + r] * rsqrtf(bnv[cb + r] + 1e-5f);
      inv[r] = iv;
      sh[r] = bnb[cb + r] - bnm[cb + r] * iv;
    }
#pragma unroll
    for(int nf = 0; nf < 4; ++nf){
      int p = pg0 + nf * 16 + lr;
#pragma unroll
      for(int r = 0; r < 4; ++r){
        size_t idx = ((size_t)(n * CD + cb + r)) * NP + p;
        out[idx] = acc[mf][nf][r] * inv[r] + sh[r] + x[idx];
      }
    }
  }
}

extern "C" void kernel_launch(void* const* d_in, const int* in_sizes, int n_in,
                              void* d_out, int out_size, void* d_ws, size_t ws_size,
                              hipStream_t stream){
  const float* x    = (const float*)d_in[0];
  const float* g_w  = (const float*)d_in[1];
  const float* g_b  = (const float*)d_in[2];
  const float* th_w = (const float*)d_in[3];
  const float* th_b = (const float*)d_in[4];
  const float* ph_w = (const float*)d_in[5];
  const float* ph_b = (const float*)d_in[6];
  const float* out_w= (const float*)d_in[7];
  const float* bng  = (const float*)d_in[8];
  const float* bnb  = (const float*)d_in[9];
  const float* bnm  = (const float*)d_in[10];
  const float* bnv  = (const float*)d_in[11];
  float* out = (float*)d_out;
  char* ws = (char*)d_ws;

  unsigned char* q8  = (unsigned char*)(ws + (size_t)(8u  << 20)); // 2 MB fp8
  unsigned char* k8  = (unsigned char*)(ws + (size_t)(12u << 20)); // 2 MB fp8 interleaved
  unsigned char* v8  = (unsigned char*)(ws + (size_t)(16u << 20)); // 2 MB fp8 tiled
  short* wb          = (short*)(ws + (size_t)(24u << 20));  // 256 KB bf16 weights
  short* po          = (short*)(ws + (size_t)(25u << 20));  // 16 MB partial O bf16
  float* psum        = (float*)(ws + (size_t)(41u << 20));  // 256 KB partial sums

  k_cvtw<<<128, 256, 0, stream>>>(g_w, th_w, ph_w, out_w, wb);
  k_proj<<<256, 512, 0, stream>>>(x, wb, g_b, th_b, ph_b, q8, k8, v8);
  k_attn<<<512, 256, 0, stream>>>(q8, k8, v8, po, psum);
  k_outproj<<<256, 512, 0, stream>>>(po, psum, wb + 98304, bng, bnb, bnm, bnv, x, out);
}

// Round 16
// 63.995 us; speedup vs baseline: 1.6952x; 1.0083x over previous
//
#include <hip/hip_runtime.h>

typedef short short8 __attribute__((ext_vector_type(8)));
typedef short short4v __attribute__((ext_vector_type(4)));
typedef float f32x4 __attribute__((ext_vector_type(4)));
typedef float f32x16 __attribute__((ext_vector_type(16)));
typedef unsigned int uint4v __attribute__((ext_vector_type(4)));
typedef unsigned int uint2v __attribute__((ext_vector_type(2)));

#define NB 4
#define CD 256
#define ID 128
#define NP 4096

static __device__ __forceinline__ short f2bf(float f){
  unsigned u = __float_as_uint(f);
  u += 0x7FFF + ((u >> 16) & 1);
  return (short)(u >> 16);
}
static __device__ __forceinline__ float bf2f(short s){
  unsigned u = ((unsigned)(unsigned short)s) << 16;
  return __uint_as_float(u);
}
static __device__ __forceinline__ unsigned cvtpk(float lo, float hi){
  unsigned r;
  asm("v_cvt_pk_bf16_f32 %0, %1, %2" : "=v"(r) : "v"(lo), "v"(hi));
  return r;
}
static __device__ __forceinline__ float fexp2(float x){
  float r;
  asm("v_exp_f32 %0, %1" : "=v"(r) : "v"(x));
  return r;
}
static __device__ __forceinline__ unsigned pack4_fp8(float a, float b, float c, float d){
  unsigned lo, hi;
  asm("v_cvt_pk_fp8_f32 %0, %1, %2" : "=v"(lo) : "v"(a), "v"(b));
  asm("v_cvt_pk_fp8_f32 %0, %1, %2" : "=v"(hi) : "v"(c), "v"(d));
  return (lo & 0xffffu) | (hi << 16);
}
static __device__ __forceinline__ unsigned char f2fp8(float v){
  unsigned u;
  asm("v_cvt_pk_fp8_f32 %0, %1, %1" : "=v"(u) : "v"(v));
  return (unsigned char)u;
}

static __device__ __forceinline__ void gload16(const void* g, void* l){
  __builtin_amdgcn_global_load_lds(
      (const __attribute__((address_space(1))) unsigned int*)g,
      (__attribute__((address_space(3))) unsigned int*)l, 16, 0, 0);
}

// ---------------- weights fp32 -> bf16 (g, theta, phi, out concatenated) ----
__global__ __launch_bounds__(256) void k_cvtw(const float* __restrict__ g_w,
    const float* __restrict__ th_w, const float* __restrict__ ph_w,
    const float* __restrict__ out_w, short* __restrict__ wb){
  int idx = (blockIdx.x * 256 + threadIdx.x) * 4;
  const float* s;
  int sel = idx >> 15;
  if(sel == 0) s = g_w; else if(sel == 1) s = th_w; else if(sel == 2) s = ph_w; else s = out_w;
  int off = idx & 32767;
  float4 v = *reinterpret_cast<const float4*>(s + off);
  short4v o = { f2bf(v.x), f2bf(v.y), f2bf(v.z), f2bf(v.w) };
  *reinterpret_cast<short4v*>(wb + idx) = o;
}

// ---------------- fused transpose + projections (LDS-staged) ----------------
__global__ __launch_bounds__(512) void k_proj(const float* __restrict__ x,
    const short* __restrict__ wb, const float* __restrict__ g_b,
    const float* __restrict__ th_b, const float* __restrict__ ph_b,
    unsigned char* __restrict__ q8, unsigned char* __restrict__ k8,
    unsigned char* __restrict__ v8){
  __shared__ __align__(16) char smem[98304];   // XF fp32 64KB | XT bf16 32KB
  char* XT = smem + 65536;
  int b = blockIdx.x;
  int n = b >> 6, pt = b & 63;
  int pb0 = pt * 64;
  int t = threadIdx.x, w = t >> 6, l = t & 63;
  int lr = l & 15, lg = l >> 4;
  int i0 = w * 16;

  const char* xg = (const char*)(x + ((size_t)n * CD) * NP + pb0);
#pragma unroll
  for(int i_ = 0; i_ < 8; ++i_){
    int dd = t * 16 + i_ * 8192;
    gload16(xg + (size_t)(dd >> 8) * 16384 + (dd & 255), smem + dd);
  }

  const short* gww = wb;
  const short* thw = wb + 32768;
  const short* phw = wb + 65536;
  short8 Wt[8], Wp[8], Wg[8];
#pragma unroll
  for(int kk = 0; kk < 8; ++kk){
    size_t wo = (size_t)(i0 + lr) * CD + kk * 32 + lg * 8;
    Wt[kk] = *reinterpret_cast<const short8*>(thw + wo);
    Wp[kk] = *reinterpret_cast<const short8*>(phw + wo);
    Wg[kk] = *reinterpret_cast<const short8*>(gww + wo);
  }
  float bt = th_b[i0 + lr];
  float bp = ph_b[i0 + lr];
  int ik = i0 + lr;
  int ip = (ik & 7) | (((ik >> 4) & 1) << 3) | (((ik >> 3) & 1) << 4) | ((ik >> 5) << 5);
  float gb[4];
#pragma unroll
  for(int r = 0; r < 4; ++r) gb[r] = g_b[i0 + lg * 4 + r];

  __syncthreads();

  {
    int p = l;
    const float* src = (const float*)smem;
    int key = (p & 15) << 4;
#pragma unroll
    for(int jj = 0; jj < 4; ++jj){
      unsigned pk4v[4];
#pragma unroll
      for(int q = 0; q < 4; ++q){
        int cp2 = w * 16 + jj * 4 + q;
        float f0 = src[(2 * cp2) * 64 + p];
        float f1 = src[(2 * cp2 + 1) * 64 + p];
        pk4v[q] = cvtpk(f0, f1);
      }
      uint4v v4 = { pk4v[0], pk4v[1], pk4v[2], pk4v[3] };
      *reinterpret_cast<uint4v*>(XT + p * 512 + ((w * 64 + jj * 16) ^ key)) = v4;
    }
  }
  __syncthreads();

  size_t vbase = ((size_t)n * 64 + pt) * 8192;
#pragma unroll
  for(int psub = 0; psub < 4; ++psub){
    int prow = psub * 16 + lr;
    short8 X[8];
#pragma unroll
    for(int kk = 0; kk < 8; ++kk)
      X[kk] = *reinterpret_cast<const short8*>(
          XT + prow * 512 + ((kk * 64 + lg * 16) ^ ((prow & 15) << 4)));
    f32x4 aT = {0.f,0.f,0.f,0.f}, aP = {0.f,0.f,0.f,0.f}, aG = {0.f,0.f,0.f,0.f};
#pragma unroll
    for(int kk = 0; kk < 8; ++kk){
      aT = __builtin_amdgcn_mfma_f32_16x16x32_bf16(X[kk], Wt[kk], aT, 0, 0, 0);
      aP = __builtin_amdgcn_mfma_f32_16x16x32_bf16(X[kk], Wp[kk], aP, 0, 0, 0);
      aG = __builtin_amdgcn_mfma_f32_16x16x32_bf16(Wg[kk], X[kk], aG, 0, 0, 0);
    }
#pragma unroll
    for(int r = 0; r < 4; ++r){
      size_t row = (size_t)(n * NP + pb0 + psub * 16 + lg * 4 + r);
      q8[row * ID + i0 + lr] = f2fp8((aT[r] + bt) * 1.44269504f);  // log2(e)
      k8[row * ID + ip]      = f2fp8(aP[r] + bp);
    }
#pragma unroll
    for(int r = 0; r < 4; ++r){
      int ii = i0 + lg * 4 + r;
      v8[vbase + (psub >> 1) * 4096 + ((lr >> 3) & 1) * 2048 + ii * 16
               + (psub & 1) * 8 + (lr & 7)] = f2fp8(aG[r] + gb[r]);
    }
  }
}

// ---------------- flash attention, fp8, swapped-QK 32x32, in-reg P ----------
// R13/R14 layouts + SOFTWARE-PIPELINED step: all 16 QK MFMAs (4 indep
// chains, both kb) issued first; SM(0) overlaps QK tail; SM(1) overlaps
// PV(0) MFMAs in the matrix pipe. Breaks the serial QK->SM->PV chain that
// left MfmaUtil and VALUBusy both at ~30%.
__global__ __launch_bounds__(256, 2) void k_attn(const unsigned char* __restrict__ q8,
    const unsigned char* __restrict__ k8, const unsigned char* __restrict__ v8,
    short* __restrict__ po, float* __restrict__ psums){
  __shared__ __align__(16) char smem[65536];
  int b = blockIdx.x;
  int xcd = b & 7;
  int n = xcd >> 1;
  int kq = ((xcd & 1) << 1) | ((b >> 3) & 1);
  int qtl = b >> 4;
  int t = threadIdx.x, w = t >> 6, l = t & 63;
  int q31 = l & 31, hi = l >> 5;
  int pbase = qtl * 128 + w * 32;

  const char* kpanel = (const char*)k8 + ((size_t)(n * NP + kq * 1024)) * ID;
  const char* vpanel = (const char*)v8 + ((size_t)n * 64 + kq * 16) * 8192;
  const char* qbase  = (const char*)q8 + ((size_t)(n * NP + pbase)) * ID;

  uint2v Qf[8];
#pragma unroll
  for(int cst = 0; cst < 8; ++cst)
    Qf[cst] = *reinterpret_cast<const uint2v*>(qbase + q31 * 128 + cst * 16 + hi * 8);

  f32x16 Of[4];
#pragma unroll
  for(int db = 0; db < 4; ++db)
#pragma unroll
    for(int r = 0; r < 16; ++r) Of[db][r] = 0.f;
  float ps = 0.f;

#define STAGE(cb, kt_) do { \
    const char* kg_ = kpanel + (size_t)(kt_) * 8192; \
    const char* vg_ = vpanel + (size_t)(kt_) * 8192; \
    char* kld_ = smem + (cb) * 8192; \
    char* vld_ = smem + 16384 + (cb) * 8192; \
    _Pragma("unroll") \
    for(int i_ = 0; i_ < 2; ++i_){ \
      int dd = t * 16 + i_ * 4096; \
      int ks = (((dd >> 4) & 63) << 7) | ((dd >> 11) << 5) | (((dd >> 10) & 1) << 4); \
      gload16(kg_ + ks, kld_ + dd); \
      gload16(vg_ + dd, vld_ + dd); \
    } \
  } while(0)

  STAGE(0, 0);
  __syncthreads();

#pragma unroll 2
  for(int kt = 0; kt < 16; ++kt){
    const int pb = kt & 1;
    if(kt + 1 < 16) STAGE(pb ^ 1, kt + 1);
    const char* Kc = smem + pb * 8192;
    const char* Vc = smem + 16384 + pb * 8192;

    // ---- QK for BOTH kb chunks: 4 independent chains, 16 MFMAs ----
    f32x16 Sa0, Sb0, Sa1, Sb1;
#pragma unroll
    for(int r = 0; r < 16; ++r){ Sa0[r] = 0.f; Sb0[r] = 0.f; Sa1[r] = 0.f; Sb1[r] = 0.f; }
    __builtin_amdgcn_s_setprio(1);
#pragma unroll
    for(int cp = 0; cp < 4; ++cp){
      uint4v Kp0 = *reinterpret_cast<const uint4v*>(
          Kc + cp * 2048 + hi * 1024 + q31 * 16);
      uint4v Kp1 = *reinterpret_cast<const uint4v*>(
          Kc + cp * 2048 + hi * 1024 + (32 + q31) * 16);
      uint2v Ka0 = { Kp0[0], Kp0[1] }, Kb0 = { Kp0[2], Kp0[3] };
      uint2v Ka1 = { Kp1[0], Kp1[1] }, Kb1 = { Kp1[2], Kp1[3] };
      long Qlo = __builtin_bit_cast(long, Qf[2*cp]);
      long Qhi = __builtin_bit_cast(long, Qf[2*cp+1]);
      Sa0 = __builtin_amdgcn_mfma_f32_32x32x16_fp8_fp8(__builtin_bit_cast(long, Ka0), Qlo, Sa0, 0, 0, 0);
      Sa1 = __builtin_amdgcn_mfma_f32_32x32x16_fp8_fp8(__builtin_bit_cast(long, Ka1), Qlo, Sa1, 0, 0, 0);
      Sb0 = __builtin_amdgcn_mfma_f32_32x32x16_fp8_fp8(__builtin_bit_cast(long, Kb0), Qhi, Sb0, 0, 0, 0);
      Sb1 = __builtin_amdgcn_mfma_f32_32x32x16_fp8_fp8(__builtin_bit_cast(long, Kb1), Qhi, Sb1, 0, 0, 0);
    }
    __builtin_amdgcn_s_setprio(0);

    // ---- SM(0): overlaps QK tail in matrix pipe ----
    long P00, P01;
    {
      float e[16];
#pragma unroll
      for(int r = 0; r < 16; ++r) e[r] = fexp2(Sa0[r] + Sb0[r] - 4.0f);
#pragma unroll
      for(int r = 0; r < 16; ++r) ps += e[r];
      unsigned u0 = pack4_fp8(e[0],  e[1],  e[2],  e[3]);
      unsigned u1 = pack4_fp8(e[4],  e[5],  e[6],  e[7]);
      unsigned u2 = pack4_fp8(e[8],  e[9],  e[10], e[11]);
      unsigned u3 = pack4_fp8(e[12], e[13], e[14], e[15]);
      asm("v_permlane32_swap_b32 %0, %1" : "+v"(u0), "+v"(u1));
      asm("v_permlane32_swap_b32 %0, %1" : "+v"(u2), "+v"(u3));
      P00 = __builtin_bit_cast(long, uint2v{u0, u1});
      P01 = __builtin_bit_cast(long, uint2v{u2, u3});
    }

    // ---- PV(0) ----
    __builtin_amdgcn_s_setprio(1);
#pragma unroll
    for(int db = 0; db < 4; ++db){
      int d = db * 32 + q31;
      uint4v Vp = *reinterpret_cast<const uint4v*>(Vc + hi * 2048 + d * 16);
      uint2v Va = { Vp[0], Vp[1] }, Vb = { Vp[2], Vp[3] };
      Of[db] = __builtin_amdgcn_mfma_f32_32x32x16_fp8_fp8(P00, __builtin_bit_cast(long, Va), Of[db], 0, 0, 0);
      Of[db] = __builtin_amdgcn_mfma_f32_32x32x16_fp8_fp8(P01, __builtin_bit_cast(long, Vb), Of[db], 0, 0, 0);
    }
    __builtin_amdgcn_s_setprio(0);

    // ---- SM(1): overlaps PV(0) MFMAs in flight ----
    long P10, P11;
    {
      float e[16];
#pragma unroll
      for(int r = 0; r < 16; ++r) e[r] = fexp2(Sa1[r] + Sb1[r] - 4.0f);
#pragma unroll
      for(int r = 0; r < 16; ++r) ps += e[r];
      unsigned u0 = pack4_fp8(e[0],  e[1],  e[2],  e[3]);
      unsigned u1 = pack4_fp8(e[4],  e[5],  e[6],  e[7]);
      unsigned u2 = pack4_fp8(e[8],  e[9],  e[10], e[11]);
      unsigned u3 = pack4_fp8(e[12], e[13], e[14], e[15]);
      asm("v_permlane32_swap_b32 %0, %1" : "+v"(u0), "+v"(u1));
      asm("v_permlane32_swap_b32 %0, %1" : "+v"(u2), "+v"(u3));
      P10 = __builtin_bit_cast(long, uint2v{u0, u1});
      P11 = __builtin_bit_cast(long, uint2v{u2, u3});
    }

    // ---- PV(1) ----
    __builtin_amdgcn_s_setprio(1);
#pragma unroll
    for(int db = 0; db < 4; ++db){
      int d = db * 32 + q31;
      uint4v Vp = *reinterpret_cast<const uint4v*>(Vc + 4096 + hi * 2048 + d * 16);
      uint2v Va = { Vp[0], Vp[1] }, Vb = { Vp[2], Vp[3] };
      Of[db] = __builtin_amdgcn_mfma_f32_32x32x16_fp8_fp8(P10, __builtin_bit_cast(long, Va), Of[db], 0, 0, 0);
      Of[db] = __builtin_amdgcn_mfma_f32_32x32x16_fp8_fp8(P11, __builtin_bit_cast(long, Vb), Of[db], 0, 0, 0);
    }
    __builtin_amdgcn_s_setprio(0);

    __syncthreads();
  }
#undef STAGE

  float pst = ps + __shfl_xor(ps, 32);
  if(hi == 0)
    psums[(size_t)kq * 16384 + n * NP + pbase + q31] = pst;

  float* ow = (float*)(smem + w * 16384);
#pragma unroll
  for(int reg = 0; reg < 16; ++reg){
    int q = (reg & 3) + 8 * (reg >> 2) + 4 * hi;
#pragma unroll
    for(int db = 0; db < 4; ++db)
      ow[q * 128 + db * 32 + q31] = Of[db][reg];
  }
  asm volatile("s_waitcnt lgkmcnt(0)" ::: "memory");
  __builtin_amdgcn_sched_barrier(0);
  short* pr = po + ((size_t)kq * 16384 + n * NP + pbase) * ID;
#pragma unroll
  for(int it = 0; it < 8; ++it){
    int o = it * 1024 + l * 16;
    int q = o >> 8, d0 = (o & 255) >> 1;
    f32x4 va = *reinterpret_cast<const f32x4*>(ow + q * 128 + d0);
    f32x4 vb = *reinterpret_cast<const f32x4*>(ow + q * 128 + d0 + 4);
    uint4v pk4 = { cvtpk(va[0], va[1]), cvtpk(va[2], va[3]),
                   cvtpk(vb[0], vb[1]), cvtpk(vb[2], vb[3]) };
    *reinterpret_cast<short8*>(pr + (size_t)q * ID + d0) = __builtin_bit_cast(short8, pk4);
  }
}

// ---------------- fused: merge 4 k-partials + 1x1 conv + BN + residual ------
__global__ __launch_bounds__(512) void k_outproj(const short* __restrict__ po,
    const float* __restrict__ psums, const short* __restrict__ ow_b,
    const float* __restrict__ bng, const float* __restrict__ bnb,
    const float* __restrict__ bnm, const float* __restrict__ bnv,
    const float* __restrict__ x, float* __restrict__ out){
  __shared__ __align__(16) short XW[64 * 128];
  int b = blockIdx.x;
  int n = b >> 6, pt = b & 63;
  int pg0 = pt * 64;
  int t = threadIdx.x, w = t >> 6, l = t & 63;
  int lr = l & 15, lg = l >> 4;

  {
    int p = t >> 3, i0 = (t & 7) * 16;
    size_t qg = (size_t)n * NP + pg0 + p;
    float den = psums[qg] + psums[16384 + qg] + psums[32768 + qg] + psums[49152 + qg];
    float inv = 1.f / (16.f * den);
    const short* pp = po + qg * ID + i0;
    int key = (p & 15) << 4;
#pragma unroll
    for(int h = 0; h < 2; ++h){
      short8 b0 = *reinterpret_cast<const short8*>(pp + h * 8);
      short8 b1 = *reinterpret_cast<const short8*>(pp + (size_t)16384 * ID + h * 8);
      short8 b2 = *reinterpret_cast<const short8*>(pp + (size_t)32768 * ID + h * 8);
      short8 b3 = *reinterpret_cast<const short8*>(pp + (size_t)49152 * ID + h * 8);
      float f[8];
#pragma unroll
      for(int j = 0; j < 8; ++j)
        f[j] = (bf2f(b0[j]) + bf2f(b1[j]) + bf2f(b2[j]) + bf2f(b3[j])) * inv;
      uint4v pkv = { cvtpk(f[0], f[1]), cvtpk(f[2], f[3]),
                     cvtpk(f[4], f[5]), cvtpk(f[6], f[7]) };
      *reinterpret_cast<short8*>((char*)XW + p * 256 + ((i0 * 2 + h * 16) ^ key)) =
          __builtin_bit_cast(short8, pkv);
    }
  }
  __syncthreads();

  int c0 = w * 32;
  f32x4 acc[2][4];
#pragma unroll
  for(int mf = 0; mf < 2; ++mf)
#pragma unroll
    for(int nf = 0; nf < 4; ++nf) acc[mf][nf] = {0.f,0.f,0.f,0.f};
#pragma unroll
  for(int kk = 0; kk < 4; ++kk){
    short8 Af[2];
#pragma unroll
    for(int mf = 0; mf < 2; ++mf)
      Af[mf] = *reinterpret_cast<const short8*>(ow_b + (size_t)(c0 + mf * 16 + lr) * ID + kk * 32 + lg * 8);
#pragma unroll
    for(int nf = 0; nf < 4; ++nf){
      int prow = nf * 16 + lr;
      short8 Bf = *reinterpret_cast<const short8*>(
          (char*)XW + prow * 256 + ((kk * 64 + lg * 16) ^ ((prow & 15) << 4)));
#pragma unroll
      for(int mf = 0; mf < 2; ++mf)
        acc[mf][nf] = __builtin_amdgcn_mfma_f32_16x16x32_bf16(Af[mf], Bf, acc[mf][nf], 0, 0, 0);
    }
  }

#pragma unroll
  for(int mf = 0; mf < 2; ++mf){
    int cb = c0 + mf * 16 + lg * 4;
    float inv[4], sh[4];
#pragma unroll
    for(int r = 0; r < 4; ++r){
      float iv = bng[cb + r] * rsqrtf(bnv[cb + r] + 1e-5f);
      inv[r] = iv;
      sh[r] = bnb[cb + r] - bnm[cb + r] * iv;
    }
#pragma unroll
    for(int nf = 0; nf < 4; ++nf){
      int p = pg0 + nf * 16 + lr;
#pragma unroll
      for(int r = 0; r < 4; ++r){
        size_t idx = ((size_t)(n * CD + cb + r)) * NP + p;
        out[idx] = acc[mf][nf][r] * inv[r] + sh[r] + x[idx];
      }
    }
  }
}

extern "C" void kernel_launch(void* const* d_in, const int* in_sizes, int n_in,
                              void* d_out, int out_size, void* d_ws, size_t ws_size,
                              hipStream_t stream){
  const float* x    = (const float*)d_in[0];
  const float* g_w  = (const float*)d_in[1];
  const float* g_b  = (const float*)d_in[2];
  const float* th_w = (const float*)d_in[3];
  const float* th_b = (const float*)d_in[4];
  const float* ph_w = (const float*)d_in[5];
  const float* ph_b = (const float*)d_in[6];
  const float* out_w= (const float*)d_in[7];
  const float* bng  = (const float*)d_in[8];
  const float* bnb  = (const float*)d_in[9];
  const float* bnm  = (const float*)d_in[10];
  const float* bnv  = (const float*)d_in[11];
  float* out = (float*)d_out;
  char* ws = (char*)d_ws;

  unsigned char* q8  = (unsigned char*)(ws + (size_t)(8u  << 20)); // 2 MB fp8
  unsigned char* k8  = (unsigned char*)(ws + (size_t)(12u << 20)); // 2 MB fp8 interleaved
  unsigned char* v8  = (unsigned char*)(ws + (size_t)(16u << 20)); // 2 MB fp8 tiled
  short* wb          = (short*)(ws + (size_t)(24u << 20));  // 256 KB bf16 weights
  short* po          = (short*)(ws + (size_t)(25u << 20));  // 16 MB partial O bf16
  float* psum        = (float*)(ws + (size_t)(41u << 20));  // 256 KB partial sums

  k_cvtw<<<128, 256, 0, stream>>>(g_w, th_w, ph_w, out_w, wb);
  k_proj<<<256, 512, 0, stream>>>(x, wb, g_b, th_b, ph_b, q8, k8, v8);
  k_attn<<<512, 256, 0, stream>>>(q8, k8, v8, po, psum);
  k_outproj<<<256, 512, 0, stream>>>(po, psum, wb + 98304, bng, bnb, bnm, bnv, x, out);
}